// Round 6
// baseline (199.419 us; speedup 1.0000x reference)
//
#include <hip/hip_runtime.h>
#include <stdint.h>

#define T_SEQ 2048
#define D_MODEL 1024
#define NH 16
#define DH 64
#define NROWS 4096  // B*T

typedef __bf16 bf16x8 __attribute__((ext_vector_type(8)));
typedef float floatx4 __attribute__((ext_vector_type(4)));
typedef short short4v __attribute__((ext_vector_type(4)));
typedef short short8v __attribute__((ext_vector_type(8)));

#define AS1 __attribute__((address_space(1)))
#define AS3 __attribute__((address_space(3)))

static __device__ __forceinline__ void gl2lds16(const unsigned short* g, unsigned short* s) {
    __builtin_amdgcn_global_load_lds((const AS1 unsigned int*)g, (AS3 unsigned int*)s, 16, 0, 0);
}

static __device__ __forceinline__ unsigned short f32_bf16(float f) {
    union { float f; unsigned int u; } c; c.f = f;
    unsigned int u = c.u;
    u = u + 0x7FFFu + ((u >> 16) & 1u);   // RNE
    return (unsigned short)(u >> 16);
}

static __device__ __forceinline__ unsigned int pack2_bf16(float a, float b) {
    return (unsigned int)f32_bf16(a) | ((unsigned int)f32_bf16(b) << 16);
}

static __device__ __forceinline__ floatx4 mfma16(bf16x8 a, bf16x8 b, floatx4 c) {
    return __builtin_amdgcn_mfma_f32_16x16x32_bf16(a, b, c, 0, 0, 0);
}

static __device__ __forceinline__ bf16x8 as_bf(short8v s) {
    union { short8v s; bf16x8 b; } u; u.s = s; return u.b;
}

#define QSCALE 0.1803368801111204f   // (1/8) * log2(e); softmax in exp2 domain
#define EXP2_SHIFT 10.0f
// s_waitcnt imm: vmcnt[3:0], expcnt[6:4]=7 (nowait), lgkmcnt[11:8]=0xF (nowait)
#define WAITCNT_VM(n) (0x0F70 | (n))

// ---------------- fused conversion kernel ----------------
__global__ __launch_bounds__(256) void k_conv_all(const float* __restrict__ x,
                                                  const float* __restrict__ Wq,
                                                  const float* __restrict__ Wk,
                                                  const float* __restrict__ Wv,
                                                  const float* __restrict__ Wo,
                                                  unsigned short* __restrict__ x_bf,
                                                  unsigned short* __restrict__ wqkv_bf,
                                                  unsigned short* __restrict__ wo_bf) {
    int b = blockIdx.x, t = threadIdx.x;
    if (b < 4096) {
        int i = b * 1024 + t * 4;
        float4 v = *(const float4*)(x + i);
        uint2 o;
        o.x = pack2_bf16(v.x, v.y);
        o.y = pack2_bf16(v.z, v.w);
        *(uint2*)(x_bf + i) = o;
    } else if (b < 7168) {
        int idx = b - 4096;
        int tensor = idx >> 10, np = idx & 1023;
        const float* src = tensor == 0 ? Wq : tensor == 1 ? Wk : Wv;
        int f = (np & 63) * 16 + (np >> 6);
        int c = t * 4;
        float4 v = *(const float4*)(src + (long)f * D_MODEL + c);
        uint2 o;
        o.x = pack2_bf16(v.x, v.y);
        o.y = pack2_bf16(v.z, v.w);
        *(uint2*)(wqkv_bf + ((long)tensor * D_MODEL + np) * D_MODEL + c) = o;
    } else {
        int n = b - 7168;
        int fp = t * 4;
        const float* row = Wo + (long)n * D_MODEL;
        unsigned short o[4];
        #pragma unroll
        for (int k = 0; k < 4; k++) {
            int f = fp + k;
            o[k] = f32_bf16(row[(f & 63) * 16 + (f >> 6)]);
        }
        *(uint2*)(wo_bf + (long)n * D_MODEL + fp) = *(const uint2*)o;
    }
}

// ---------------- QKV GEMM: 256x256 tile, 8-wave, 4-phase K-loop ----------------
// r12: stage pieces back to the measured-good 3/3/2 spread over q0-q2 (r11's
// all-at-q0 burst cost ~10us: 64 simultaneous DMA issues swamp the TA queue).
// Grid 192 (16x12), XCD-chunked; 1 block/CU.
__global__ __launch_bounds__(512, 2) void k_qkv256(const unsigned short* __restrict__ A,
                                                   const unsigned short* __restrict__ W,
                                                   const float* __restrict__ bq,
                                                   const float* __restrict__ bk,
                                                   const float* __restrict__ bv,
                                                   unsigned short* __restrict__ out_bf,
                                                   unsigned short* __restrict__ vtg) {
    __shared__ unsigned short lds[2 * 32768];   // buf: A[256][64] | B[256][64]
    const int tid = threadIdx.x;
    const int w = tid >> 6, l = tid & 63;
    const int lrow = l & 15, lq = l >> 4;
    const int sw8 = lrow & 7;
    const int wm_id = w >> 2, wn_id = w & 3;
    const int L = blockIdx.x;
    const int bx = (L & 7) * 2 + ((L >> 3) & 1);
    const int by = L >> 4;                       // 0..11
    const long am0 = (long)bx * 256;
    const long wn0 = (long)by * 256;

    const int rl = l >> 3;                       // staging: row within 8-row chunk
    const int gl = ((l & 7) ^ rl) * 8;           // staging: swizzled granule (shorts)

    floatx4 acc[8][4] = {};

    // piece 0..3: A chunks; 4..7: B chunks. 1 DMA instr/thread/piece.
    auto stage_piece = [&](int ki, int sel, int piece) {
        int c = piece & 3;
        int chunk = c * 8 + w;                   // 0..31 (8 rows each)
        int k0 = ki * 64;
        if (piece < 4) {
            gl2lds16(A + (am0 + chunk * 8 + rl) * D_MODEL + k0 + gl,
                     lds + sel * 32768 + chunk * 512);
        } else {
            gl2lds16(W + (wn0 + chunk * 8 + rl) * D_MODEL + k0 + gl,
                     lds + sel * 32768 + 16384 + chunk * 512);
        }
    };

    // prologue: tile 0 fully staged
    #pragma unroll
    for (int pc = 0; pc < 8; pc++) stage_piece(0, 0, pc);
    __builtin_amdgcn_s_waitcnt(WAITCNT_VM(0));
    __builtin_amdgcn_s_barrier();

    for (int t = 0; t < 16; t++) {
        const int sel = t & 1;
        const unsigned short* Ab = lds + sel * 32768;
        const unsigned short* Bb = Ab + 16384;
        bf16x8 bfr[4];
        #pragma unroll
        for (int q = 0; q < 4; q++) {
            const int ks = q >> 1, mh = q & 1;
            if (mh == 0) {
                #pragma unroll
                for (int nt = 0; nt < 4; nt++) {
                    int row = wn_id * 64 + nt * 16 + lrow;
                    bfr[nt] = *(const bf16x8*)(Bb + row * 64 + (((ks * 4 + lq) ^ sw8) * 8));
                }
            }
            bf16x8 af[4];
            #pragma unroll
            for (int j = 0; j < 4; j++) {
                int row = wm_id * 128 + (mh * 4 + j) * 16 + lrow;
                af[j] = *(const bf16x8*)(Ab + row * 64 + (((ks * 4 + lq) ^ sw8) * 8));
            }
            if (t < 15) {
                // front-loaded: 3,3,2,0 pieces over q=0..3
                if (q == 0) {
                    stage_piece(t + 1, sel ^ 1, 0);
                    stage_piece(t + 1, sel ^ 1, 1);
                    stage_piece(t + 1, sel ^ 1, 2);
                } else if (q == 1) {
                    stage_piece(t + 1, sel ^ 1, 3);
                    stage_piece(t + 1, sel ^ 1, 4);
                    stage_piece(t + 1, sel ^ 1, 5);
                } else if (q == 2) {
                    stage_piece(t + 1, sel ^ 1, 6);
                    stage_piece(t + 1, sel ^ 1, 7);
                }
            }
            __builtin_amdgcn_s_barrier();
            __builtin_amdgcn_s_setprio(1);
            #pragma unroll
            for (int j = 0; j < 4; j++)
                #pragma unroll
                for (int nt = 0; nt < 4; nt++)
                    acc[mh * 4 + j][nt] = mfma16(af[j], bfr[nt], acc[mh * 4 + j][nt]);
            __builtin_amdgcn_s_setprio(0);
            if (q == 3 && t < 15)
                __builtin_amdgcn_s_waitcnt(WAITCNT_VM(0));  // tile t+1 landed
            __builtin_amdgcn_s_barrier();
        }
    }

    // ---- epilogue: Q/K scatter to [b,h,i,d]; V to permuted vtg ----
    int tensor = by >> 2;                    // 0=Q 1=K 2=V
    int nbase = (by & 3) * 256;
    const float* bias = tensor == 0 ? bq : tensor == 1 ? bk : bv;
    float scale = tensor == 0 ? QSCALE : 1.0f;
    if (tensor < 2) {
        unsigned short* outt = out_bf + (size_t)tensor * (32u * T_SEQ * DH);
        #pragma unroll
        for (int mt = 0; mt < 8; mt++) {
            #pragma unroll
            for (int nt = 0; nt < 4; nt++) {
                int n = nbase + wn_id * 64 + nt * 16 + lrow;     // n' = h*64+d
                int h = n >> 6, d = n & 63;
                float bb = bias[d * 16 + h];
                #pragma unroll
                for (int r = 0; r < 4; r++) {
                    int row = (int)am0 + wm_id * 128 + mt * 16 + lq * 4 + r;
                    float v = (acc[mt][nt][r] + bb) * scale;
                    int b = row >> 11, i = row & 2047;
                    long idx = ((long)(b * 16 + h) * T_SEQ + i) * DH + d;
                    outt[idx] = f32_bf16(v);
                }
            }
        }
    } else {
        int row0 = (int)am0 + wm_id * 128;           // multiple of 128
        int b = row0 >> 11;
        int blkb = (row0 & 2047) >> 6;
        // vtg j'-slot permutation (within each 64-token block): position
        // g*32 + lq*8 + nt'*4 + r holds token (g*2+nt')*16 + lq*4 + r.
        #pragma unroll
        for (int nt = 0; nt < 4; nt++) {
            int n = nbase + wn_id * 64 + nt * 16 + lrow;
            int h = n >> 6, d = n & 63;
            float bb = bias[d * 16 + h];
            #pragma unroll
            for (int mt = 0; mt < 8; mt++) {
                int blk = blkb + (mt >> 2);
                int m4 = mt & 3;
                long base = (((long)(b * 16 + h) * 64 + d) * 32 + blk) * 64;
                uint2 o;
                o.x = pack2_bf16(acc[mt][nt][0] + bb, acc[mt][nt][1] + bb);
                o.y = pack2_bf16(acc[mt][nt][2] + bb, acc[mt][nt][3] + bb);
                *(uint2*)(vtg + base + (m4 >> 1) * 32 + lq * 8 + (m4 & 1) * 4) = o;
            }
        }
    }
}

// ---------------- GEMM: C = A(bf16) @ W(bf16)^T, K = 1024 ----------------
// O-proj (grid 512): dbuf manual partial-vmcnt (48 KB, 2 blocks/CU).
// XOR-swizzled LDS (0 bank conflicts measured), XCD-aware block swizzle.
template <int BN, int MODE>
__global__ __launch_bounds__(256) void k_gemm(const unsigned short* __restrict__ A,
                                              const unsigned short* __restrict__ W,
                                              const float* __restrict__ b0,
                                              const float* __restrict__ resid,
                                              float* __restrict__ out_f32) {
    constexpr int NT = BN / 32;
    constexpr int NCB = BN / 32;
    constexpr int NDMA = 4 + NCB;            // DMA instrs per thread per stage
    __shared__ unsigned short lds_a[2 * 128 * 64];
    __shared__ unsigned short lds_b[2 * BN * 64];
    const int tid = threadIdx.x;
    const int w = tid >> 6, l = tid & 63;
    const int lrow = l & 15, lq = l >> 4;
    const int wm = (w >> 1) * 64, wn = (w & 1) * (BN / 2);
    const int L = blockIdx.x;
    const int bx = (L & 7) * 4 + ((L >> 3) & 3);
    const int by = L >> 5;
    const long am0 = (long)bx * 128;
    const long wn0 = (long)by * BN;

    floatx4 acc[4][NT] = {};
    const int grow = l >> 3;
    const int gcol = ((l & 7) ^ grow) * 8;   // column-group XOR swizzle (global side)
    const int sw8 = (lrow & 7);

    auto stage = [&](int ki, int sel) {
        unsigned short* la = lds_a + sel * 8192;
        unsigned short* lb = lds_b + sel * (BN * 64);
        int k0 = ki * 64;
        #pragma unroll
        for (int c = 0; c < 4; c++) {
            int chunk = w * 4 + c;
            gl2lds16(A + (am0 + chunk * 8 + grow) * D_MODEL + k0 + gcol, la + chunk * 512);
        }
        #pragma unroll
        for (int c = 0; c < NCB; c++) {
            int chunk = w * NCB + c;
            gl2lds16(W + (wn0 + chunk * 8 + grow) * D_MODEL + k0 + gcol, lb + chunk * 512);
        }
    };

    auto compute = [&](const unsigned short* la, const unsigned short* lb) {
        bf16x8 af[4][2], bfr[NT][2];
        #pragma unroll
        for (int mt = 0; mt < 4; mt++)
            #pragma unroll
            for (int ks = 0; ks < 2; ks++)
                af[mt][ks] = *(const bf16x8*)(la + (wm + mt * 16 + lrow) * 64 +
                                              (((ks * 4 + lq) ^ sw8) * 8));
        #pragma unroll
        for (int nt = 0; nt < NT; nt++)
            #pragma unroll
            for (int ks = 0; ks < 2; ks++)
                bfr[nt][ks] = *(const bf16x8*)(lb + (wn + nt * 16 + lrow) * 64 +
                                               (((ks * 4 + lq) ^ sw8) * 8));
        #pragma unroll
        for (int mt = 0; mt < 4; mt++)
            #pragma unroll
            for (int nt = 0; nt < NT; nt++)
                #pragma unroll
                for (int ks = 0; ks < 2; ks++)
                    acc[mt][nt] = mfma16(af[mt][ks], bfr[nt][ks], acc[mt][nt]);
    };

    stage(0, 0);
    for (int i = 0; i < 16; i++) {
        const int cur = i & 1;
        if (i < 15) {
            stage(i + 1, 1 - cur);
            __builtin_amdgcn_s_waitcnt(WAITCNT_VM(NDMA));  // drain stage(i), keep stage(i+1)
        } else {
            __builtin_amdgcn_s_waitcnt(WAITCNT_VM(0));
        }
        __builtin_amdgcn_s_barrier();
        compute(lds_a + cur * 8192, lds_b + cur * (BN * 64));
        __builtin_amdgcn_s_barrier();   // raw: reads of buf[cur] done before restage (i+2)
    }

    #pragma unroll
    for (int mt = 0; mt < 4; mt++) {
        #pragma unroll
        for (int nt = 0; nt < NT; nt++) {
            int n = (int)wn0 + wn + nt * 16 + lrow;
            float bb = b0[n];
            #pragma unroll
            for (int r = 0; r < 4; r++) {
                int row = (int)am0 + wm + mt * 16 + lq * 4 + r;
                long idx = (long)row * D_MODEL + n;
                out_f32[idx] = acc[mt][nt][r] + bb + resid[idx];
            }
        }
    }
}

// ---------------- attention: ring-4 + single barrier + cross-tile interleave ----
// r12: keeps r11's ring-4 / 1-barrier / counted-vmcnt sync, but the body now
// interleaves PV(t-1) MFMAs with sp4(t) TRANS at dt granularity (4 MFMA + 8
// exp2 + 4 perm per step) — the two are independent (PV(t-1) needs only
// pf(t-1)+V(t-1); sp4(t) needs only QK(t)), so each wave keeps BOTH pipes fed
// instead of alternating long MFMA-only / VALU-only bursts (r11 measured
// MfmaUtil 33 + VALUBusy 40: serialized).
// Ring safety (stage AFTER body): body(t) reads K(t)=slot t&3, V(t-1)=slot
// (t-1)&3; stage S(t+2)->slot (t+2)&3 never aliases (distance 2,3 mod 4);
// laggard waves are past barrier(t) so read only slots t, t-1. Last reader of
// slot s is body(s+1) (V); reuse by S(s+4) is issued after barrier(s+2) which
// guarantees body(s+1) complete.
// vmcnt ledger: before barrier(t) outstanding = {S(t),S(t+1)} = 8 -> vmcnt(4)
// drains S(t); t=31: only S(31) -> vmcnt(0).
// Accumulation order per accumulator unchanged -> bitwise-identical output.
__global__ __launch_bounds__(256) void k_attn(const unsigned short* __restrict__ q_ws,
                                              const unsigned short* __restrict__ k_ws,
                                              const unsigned short* __restrict__ vtg,
                                              unsigned short* __restrict__ att) {
    __shared__ unsigned short kbuf[4 * 4096];
    __shared__ unsigned short vbuf[4 * 4096];
    const int tid = threadIdx.x;
    const int w = tid >> 6, l = tid & 63;
    const int lrow = l & 15, lq = l >> 4;
    const int sw = lrow & 7;
    const int L = blockIdx.x;
    const int bh = (L & 7) * 4 + ((L >> 3) & 3);   // 4 bh per XCD -> K/V L2-resident
    const int i0 = (L >> 5) * 128;
    const unsigned short* kh = k_ws + (long)bh * T_SEQ * DH;
    const unsigned short* vh = vtg + (long)bh * 64 * T_SEQ;  // [d][blk][j'-permuted]

    const int rl = l >> 3;                     // staging: row within 8-row chunk
    const int gl = ((l & 7) ^ rl) * 8;         // staging: swizzled granule (shorts)

    bf16x8 qf[2][2];
    #pragma unroll
    for (int qt = 0; qt < 2; qt++) {
        const unsigned short* qp =
            q_ws + ((long)bh * T_SEQ + i0 + w * 32 + qt * 16 + lrow) * DH + lq * 8;
        qf[qt][0] = *(const bf16x8*)qp;
        qf[qt][1] = *(const bf16x8*)(qp + 32);
    }
    floatx4 o_acc[2][4] = {};
    floatx4 l_acc[2] = {};
    const short8v ones8s = {0x3F80, 0x3F80, 0x3F80, 0x3F80, 0x3F80, 0x3F80, 0x3F80, 0x3F80};
    const bf16x8 ones8 = as_bf(ones8s);

    // one K/V tile stage: 4 DMA instrs per thread (2 K + 2 V)
    auto stage = [&](int jt, int sel) {
        unsigned short* kd = kbuf + sel * 4096 + (w * 2) * 512;
        unsigned short* vd = vbuf + sel * 4096 + (w * 2) * 512;
        #pragma unroll
        for (int c = 0; c < 2; c++) {
            int row = w * 16 + c * 8 + rl;     // 0..63
            gl2lds16(kh + ((long)(jt * 64 + row)) * 64 + gl, kd + c * 512);
        }
        #pragma unroll
        for (int c = 0; c < 2; c++) {
            int row = w * 16 + c * 8 + rl;
            gl2lds16(vh + ((long)row * 32 + jt) * 64 + gl, vd + c * 512);
        }
    };

    // p = exp2(s); pack 4 bf16 (truncation via perm)
    auto sp4 = [&](floatx4 s) -> short4v {
        float p0 = __builtin_amdgcn_exp2f(s[0]);
        float p1 = __builtin_amdgcn_exp2f(s[1]);
        float p2 = __builtin_amdgcn_exp2f(s[2]);
        float p3 = __builtin_amdgcn_exp2f(s[3]);
        uint2 pk;
        pk.x = __builtin_amdgcn_perm(__float_as_uint(p1), __float_as_uint(p0), 0x07060302);
        pk.y = __builtin_amdgcn_perm(__float_as_uint(p3), __float_as_uint(p2), 0x07060302);
        union { uint2 u; short4v s4; } cv; cv.u = pk;
        return cv.s4;
    };

    // O^T += V^T * P for one dt, both q-tiles, K=32 (two j-halves g=0/1)
    auto pv_dt = [&](const unsigned short* vb_, int dt,
                     short8v (&p0)[2], short8v (&p1)[2]) {
        const unsigned short* vp = vb_ + (dt * 16 + lrow) * 64;
        bf16x8 vg0 = *(const bf16x8*)(vp + ((lq ^ sw) * 8));         // granule lq   (j 0..31)
        bf16x8 vg1 = *(const bf16x8*)(vp + (((4 + lq) ^ sw) * 8));   // granule 4+lq (j 32..63)
        o_acc[0][dt] = mfma16(vg0, as_bf(p0[0]), o_acc[0][dt]);
        o_acc[0][dt] = mfma16(vg1, as_bf(p0[1]), o_acc[0][dt]);
        o_acc[1][dt] = mfma16(vg0, as_bf(p1[0]), o_acc[1][dt]);
        o_acc[1][dt] = mfma16(vg1, as_bf(p1[1]), o_acc[1][dt]);
    };

    // QK^T for tile (kb_), writing s0/s1
    auto qk = [&](const unsigned short* kb_, floatx4 (&s0)[4], floatx4 (&s1)[4]) {
        #pragma unroll
        for (int nt = 0; nt < 4; nt++) {
            const unsigned short* kp = kb_ + (nt * 16 + lrow) * 64;
            bf16x8 ka = *(const bf16x8*)(kp + ((lq ^ sw) * 8));
            bf16x8 kb2 = *(const bf16x8*)(kp + (((lq + 4) ^ sw) * 8));
            floatx4 c0 = {-EXP2_SHIFT, -EXP2_SHIFT, -EXP2_SHIFT, -EXP2_SHIFT};
            floatx4 c1 = c0;
            c0 = mfma16(ka, qf[0][0], c0);
            c0 = mfma16(kb2, qf[0][1], c0);
            c1 = mfma16(ka, qf[1][0], c1);
            c1 = mfma16(kb2, qf[1][1], c1);
            s0[nt] = c0;
            s1[nt] = c1;
        }
    };

    // body(t): QK(t), then { PV(t-1) using pp ∥ sp4(t) } interleaved, l_acc(t);
    // produces pc = pf(t).
    auto body = [&](const unsigned short* kb_, const unsigned short* vb_,
                    short8v (&pp0)[2], short8v (&pp1)[2],
                    short8v (&pc0)[2], short8v (&pc1)[2]) {
        floatx4 s0[4], s1[4];
        qk(kb_, s0, s1);
        short4v u0[4], u1[4];
        #pragma unroll
        for (int dt = 0; dt < 4; dt++) {
            pv_dt(vb_, dt, pp0, pp1);      // 4 MFMA (prev tile)
            u0[dt] = sp4(s0[dt]);          // 4 exp2 + 2 perm (this tile)
            u1[dt] = sp4(s1[dt]);
        }
        pc0[0] = __builtin_shufflevector(u0[0], u0[1], 0, 1, 2, 3, 4, 5, 6, 7);
        pc0[1] = __builtin_shufflevector(u0[2], u0[3], 0, 1, 2, 3, 4, 5, 6, 7);
        pc1[0] = __builtin_shufflevector(u1[0], u1[1], 0, 1, 2, 3, 4, 5, 6, 7);
        pc1[1] = __builtin_shufflevector(u1[2], u1[3], 0, 1, 2, 3, 4, 5, 6, 7);
        l_acc[0] = mfma16(ones8, as_bf(pc0[0]), l_acc[0]);
        l_acc[0] = mfma16(ones8, as_bf(pc0[1]), l_acc[0]);
        l_acc[1] = mfma16(ones8, as_bf(pc1[0]), l_acc[1]);
        l_acc[1] = mfma16(ones8, as_bf(pc1[1]), l_acc[1]);
    };

    short8v pA0[2], pA1[2], pB0[2], pB1[2];

    // ---- prologue ----
    stage(0, 0);
    stage(1, 1);
    __builtin_amdgcn_s_waitcnt(WAITCNT_VM(4));   // drain S(0), keep S(1)
    __builtin_amdgcn_s_barrier();
    {   // tile 0: QK + sp4 + l_acc only (no PV); produces pA
        floatx4 s0[4], s1[4];
        qk(kbuf, s0, s1);
        short4v u0[4], u1[4];
        #pragma unroll
        for (int dt = 0; dt < 4; dt++) {
            u0[dt] = sp4(s0[dt]);
            u1[dt] = sp4(s1[dt]);
        }
        pA0[0] = __builtin_shufflevector(u0[0], u0[1], 0, 1, 2, 3, 4, 5, 6, 7);
        pA0[1] = __builtin_shufflevector(u0[2], u0[3], 0, 1, 2, 3, 4, 5, 6, 7);
        pA1[0] = __builtin_shufflevector(u1[0], u1[1], 0, 1, 2, 3, 4, 5, 6, 7);
        pA1[1] = __builtin_shufflevector(u1[2], u1[3], 0, 1, 2, 3, 4, 5, 6, 7);
        l_acc[0] = mfma16(ones8, as_bf(pA0[0]), l_acc[0]);
        l_acc[0] = mfma16(ones8, as_bf(pA0[1]), l_acc[0]);
        l_acc[1] = mfma16(ones8, as_bf(pA1[0]), l_acc[1]);
        l_acc[1] = mfma16(ones8, as_bf(pA1[1]), l_acc[1]);
    }
    stage(2, 2);

    // ---- main loop: tiles 1..30, explicitly paired so pf rotates in regs ----
    for (int t = 1; t < 31; t += 2) {
        // body(t) (odd): consume pA -> produce pB
        __builtin_amdgcn_s_waitcnt(WAITCNT_VM(4));   // drain S(t), keep S(t+1)
        __builtin_amdgcn_s_barrier();
        body(kbuf + (t & 3) * 4096, vbuf + ((t - 1) & 3) * 4096,
             pA0, pA1, pB0, pB1);
        stage(t + 2, (t + 2) & 3);
        // body(t+1) (even): consume pB -> produce pA
        __builtin_amdgcn_s_waitcnt(WAITCNT_VM(4));   // drain S(t+1), keep S(t+2)
        __builtin_amdgcn_s_barrier();
        body(kbuf + ((t + 1) & 3) * 4096, vbuf + (t & 3) * 4096,
             pB0, pB1, pA0, pA1);
        if (t < 29) stage(t + 3, (t + 3) & 3);
    }

    // ---- tile 31: consume pA -> produce pB ----
    __builtin_amdgcn_s_waitcnt(WAITCNT_VM(0));   // drain S(31)
    __builtin_amdgcn_s_barrier();
    body(kbuf + (31 & 3) * 4096, vbuf + (30 & 3) * 4096, pA0, pA1, pB0, pB1);

    // ---- epilogue: PV(31) ----
    #pragma unroll
    for (int dt = 0; dt < 4; dt++) pv_dt(vbuf + (31 & 3) * 4096, dt, pB0, pB1);

    int h = bh & 15, b = bh >> 4;
    #pragma unroll
    for (int qt = 0; qt < 2; qt++) {
        float rl2 = 1.0f / l_acc[qt][0];
        int i = i0 + w * 32 + qt * 16 + lrow;
        unsigned short* orow = att + ((long)(b * T_SEQ + i)) * D_MODEL + h * 64;
        #pragma unroll
        for (int dt = 0; dt < 4; dt++) {
            uint2 o;
            o.x = pack2_bf16(o_acc[qt][dt][0] * rl2, o_acc[qt][dt][1] * rl2);
            o.y = pack2_bf16(o_acc[qt][dt][2] * rl2, o_acc[qt][dt][3] * rl2);
            *(uint2*)(orow + dt * 16 + lq * 4) = o;
        }
    }
}

// ---------------- LayerNorm in-place on d_out ----------------
__global__ __launch_bounds__(256) void k_ln(float* __restrict__ io,
                                            const float* __restrict__ gamma,
                                            const float* __restrict__ beta) {
    int row = blockIdx.x, t = threadIdx.x;
    float* p = io + (long)row * D_MODEL + t * 4;
    float4 v = *(float4*)p;
    float s = v.x + v.y + v.z + v.w;
    float ss = v.x * v.x + v.y * v.y + v.z * v.z + v.w * v.w;
    #pragma unroll
    for (int m = 1; m < 64; m <<= 1) {
        s += __shfl_xor(s, m);
        ss += __shfl_xor(ss, m);
    }
    __shared__ float red[8];
    if ((t & 63) == 0) { red[t >> 6] = s; red[4 + (t >> 6)] = ss; }
    __syncthreads();
    s = red[0] + red[1] + red[2] + red[3];
    ss = red[4] + red[5] + red[6] + red[7];
    float mu = s * (1.0f / 1024.0f);
    float var = ss * (1.0f / 1024.0f) - mu * mu;
    float rstd = rsqrtf(var + 1e-5f);
    float4 g = *(const float4*)(gamma + t * 4);
    float4 be = *(const float4*)(beta + t * 4);
    float4 o;
    o.x = (v.x - mu) * rstd * g.x + be.x;
    o.y = (v.y - mu) * rstd * g.y + be.y;
    o.z = (v.z - mu) * rstd * g.z + be.z;
    o.w = (v.w - mu) * rstd * g.w + be.w;
    *(float4*)p = o;
}

extern "C" void kernel_launch(void* const* d_in, const int* in_sizes, int n_in,
                              void* d_out, int out_size, void* d_ws, size_t ws_size,
                              hipStream_t stream) {
    const float* x = (const float*)d_in[0];
    const float* Wq = (const float*)d_in[1];
    const float* bq = (const float*)d_in[2];
    const float* Wk = (const float*)d_in[3];
    const float* bk = (const float*)d_in[4];
    const float* Wv = (const float*)d_in[5];
    const float* bv = (const float*)d_in[6];
    const float* Wo = (const float*)d_in[7];
    const float* bo = (const float*)d_in[8];
    const float* gamma = (const float*)d_in[9];
    const float* beta = (const float*)d_in[10];
    float* out = (float*)d_out;

    char* ws = (char*)d_ws;
    unsigned short* x_bf = (unsigned short*)(ws);                       // 0-8 MB (reused as att)
    unsigned short* wqkv_bf = (unsigned short*)(ws + ((size_t)8 << 20));// 8-14 MB
    unsigned short* wo_bf = (unsigned short*)(ws + ((size_t)14 << 20)); // 14-16 MB
    unsigned short* qkv_ws = (unsigned short*)(ws + ((size_t)16 << 20));// 16-40 MB (q|k|vt)
    unsigned short* att = x_bf;  // alias: x_bf dead after QKV GEMM

    unsigned short* q_ws = qkv_ws;
    unsigned short* k_ws = qkv_ws + (size_t)32 * T_SEQ * DH;
    unsigned short* vtg = qkv_ws + (size_t)64 * T_SEQ * DH;

    k_conv_all<<<8192, 256, 0, stream>>>(x, Wq, Wk, Wv, Wo, x_bf, wqkv_bf, wo_bf);

    // fused QKV GEMM: 256x256 tiles, N = 3072, grid 192 (XCD-chunked)
    k_qkv256<<<192, 512, 0, stream>>>(x_bf, wqkv_bf, bq, bk, bv, qkv_ws, vtg);

    k_attn<<<512, 256, 0, stream>>>(q_ws, k_ws, vtg, att);

    // O-projection + bias + residual: N = 1024, 1D grid with XCD swizzle
    k_gemm<64, 1><<<512, 256, 0, stream>>>(
        att, wo_bf, bo, x, out);

    k_ln<<<NROWS, 256, 0, stream>>>(out, gamma, beta);
}

// Round 7
// 195.180 us; speedup vs baseline: 1.0217x; 1.0217x over previous
//
#include <hip/hip_runtime.h>
#include <stdint.h>

#define T_SEQ 2048
#define D_MODEL 1024
#define NH 16
#define DH 64
#define NROWS 4096  // B*T

typedef __bf16 bf16x8 __attribute__((ext_vector_type(8)));
typedef float floatx4 __attribute__((ext_vector_type(4)));
typedef short short4v __attribute__((ext_vector_type(4)));
typedef short short8v __attribute__((ext_vector_type(8)));

#define AS1 __attribute__((address_space(1)))
#define AS3 __attribute__((address_space(3)))

static __device__ __forceinline__ void gl2lds16(const unsigned short* g, unsigned short* s) {
    __builtin_amdgcn_global_load_lds((const AS1 unsigned int*)g, (AS3 unsigned int*)s, 16, 0, 0);
}

static __device__ __forceinline__ unsigned short f32_bf16(float f) {
    union { float f; unsigned int u; } c; c.f = f;
    unsigned int u = c.u;
    u = u + 0x7FFFu + ((u >> 16) & 1u);   // RNE
    return (unsigned short)(u >> 16);
}

static __device__ __forceinline__ unsigned int pack2_bf16(float a, float b) {
    return (unsigned int)f32_bf16(a) | ((unsigned int)f32_bf16(b) << 16);
}

static __device__ __forceinline__ floatx4 mfma16(bf16x8 a, bf16x8 b, floatx4 c) {
    return __builtin_amdgcn_mfma_f32_16x16x32_bf16(a, b, c, 0, 0, 0);
}

static __device__ __forceinline__ bf16x8 as_bf(short8v s) {
    union { short8v s; bf16x8 b; } u; u.s = s; return u.b;
}

#define QSCALE 0.1803368801111204f   // (1/8) * log2(e); softmax in exp2 domain
#define EXP2_SHIFT 10.0f
// s_waitcnt imm: vmcnt[3:0], expcnt[6:4]=7 (nowait), lgkmcnt[11:8]=0xF (nowait)
#define WAITCNT_VM(n) (0x0F70 | (n))

// ---------------- fused conversion kernel ----------------
__global__ __launch_bounds__(256) void k_conv_all(const float* __restrict__ x,
                                                  const float* __restrict__ Wq,
                                                  const float* __restrict__ Wk,
                                                  const float* __restrict__ Wv,
                                                  const float* __restrict__ Wo,
                                                  unsigned short* __restrict__ x_bf,
                                                  unsigned short* __restrict__ wqkv_bf,
                                                  unsigned short* __restrict__ wo_bf) {
    int b = blockIdx.x, t = threadIdx.x;
    if (b < 4096) {
        int i = b * 1024 + t * 4;
        float4 v = *(const float4*)(x + i);
        uint2 o;
        o.x = pack2_bf16(v.x, v.y);
        o.y = pack2_bf16(v.z, v.w);
        *(uint2*)(x_bf + i) = o;
    } else if (b < 7168) {
        int idx = b - 4096;
        int tensor = idx >> 10, np = idx & 1023;
        const float* src = tensor == 0 ? Wq : tensor == 1 ? Wk : Wv;
        int f = (np & 63) * 16 + (np >> 6);
        int c = t * 4;
        float4 v = *(const float4*)(src + (long)f * D_MODEL + c);
        uint2 o;
        o.x = pack2_bf16(v.x, v.y);
        o.y = pack2_bf16(v.z, v.w);
        *(uint2*)(wqkv_bf + ((long)tensor * D_MODEL + np) * D_MODEL + c) = o;
    } else {
        int n = b - 7168;
        int fp = t * 4;
        const float* row = Wo + (long)n * D_MODEL;
        unsigned short o[4];
        #pragma unroll
        for (int k = 0; k < 4; k++) {
            int f = fp + k;
            o[k] = f32_bf16(row[(f & 63) * 16 + (f >> 6)]);
        }
        *(uint2*)(wo_bf + (long)n * D_MODEL + fp) = *(const uint2*)o;
    }
}

// ---------------- QKV GEMM: 256x256 tile, 8-wave, 4-phase K-loop ----------------
// Stage pieces 3/3/2 over q0-q2 (measured-good in r4/r6). Grid 192 (16x12),
// XCD-chunked; 1 block/CU.
__global__ __launch_bounds__(512, 2) void k_qkv256(const unsigned short* __restrict__ A,
                                                   const unsigned short* __restrict__ W,
                                                   const float* __restrict__ bq,
                                                   const float* __restrict__ bk,
                                                   const float* __restrict__ bv,
                                                   unsigned short* __restrict__ out_bf,
                                                   unsigned short* __restrict__ vtg) {
    __shared__ unsigned short lds[2 * 32768];   // buf: A[256][64] | B[256][64]
    const int tid = threadIdx.x;
    const int w = tid >> 6, l = tid & 63;
    const int lrow = l & 15, lq = l >> 4;
    const int sw8 = lrow & 7;
    const int wm_id = w >> 2, wn_id = w & 3;
    const int L = blockIdx.x;
    const int bx = (L & 7) * 2 + ((L >> 3) & 1);
    const int by = L >> 4;                       // 0..11
    const long am0 = (long)bx * 256;
    const long wn0 = (long)by * 256;

    const int rl = l >> 3;                       // staging: row within 8-row chunk
    const int gl = ((l & 7) ^ rl) * 8;           // staging: swizzled granule (shorts)

    floatx4 acc[8][4] = {};

    // piece 0..3: A chunks; 4..7: B chunks. 1 DMA instr/thread/piece.
    auto stage_piece = [&](int ki, int sel, int piece) {
        int c = piece & 3;
        int chunk = c * 8 + w;                   // 0..31 (8 rows each)
        int k0 = ki * 64;
        if (piece < 4) {
            gl2lds16(A + (am0 + chunk * 8 + rl) * D_MODEL + k0 + gl,
                     lds + sel * 32768 + chunk * 512);
        } else {
            gl2lds16(W + (wn0 + chunk * 8 + rl) * D_MODEL + k0 + gl,
                     lds + sel * 32768 + 16384 + chunk * 512);
        }
    };

    // prologue: tile 0 fully staged
    #pragma unroll
    for (int pc = 0; pc < 8; pc++) stage_piece(0, 0, pc);
    __builtin_amdgcn_s_waitcnt(WAITCNT_VM(0));
    __builtin_amdgcn_s_barrier();

    for (int t = 0; t < 16; t++) {
        const int sel = t & 1;
        const unsigned short* Ab = lds + sel * 32768;
        const unsigned short* Bb = Ab + 16384;
        bf16x8 bfr[4];
        #pragma unroll
        for (int q = 0; q < 4; q++) {
            const int ks = q >> 1, mh = q & 1;
            if (mh == 0) {
                #pragma unroll
                for (int nt = 0; nt < 4; nt++) {
                    int row = wn_id * 64 + nt * 16 + lrow;
                    bfr[nt] = *(const bf16x8*)(Bb + row * 64 + (((ks * 4 + lq) ^ sw8) * 8));
                }
            }
            bf16x8 af[4];
            #pragma unroll
            for (int j = 0; j < 4; j++) {
                int row = wm_id * 128 + (mh * 4 + j) * 16 + lrow;
                af[j] = *(const bf16x8*)(Ab + row * 64 + (((ks * 4 + lq) ^ sw8) * 8));
            }
            if (t < 15) {
                // front-loaded: 3,3,2,0 pieces over q=0..3
                if (q == 0) {
                    stage_piece(t + 1, sel ^ 1, 0);
                    stage_piece(t + 1, sel ^ 1, 1);
                    stage_piece(t + 1, sel ^ 1, 2);
                } else if (q == 1) {
                    stage_piece(t + 1, sel ^ 1, 3);
                    stage_piece(t + 1, sel ^ 1, 4);
                    stage_piece(t + 1, sel ^ 1, 5);
                } else if (q == 2) {
                    stage_piece(t + 1, sel ^ 1, 6);
                    stage_piece(t + 1, sel ^ 1, 7);
                }
            }
            __builtin_amdgcn_s_barrier();
            __builtin_amdgcn_s_setprio(1);
            #pragma unroll
            for (int j = 0; j < 4; j++)
                #pragma unroll
                for (int nt = 0; nt < 4; nt++)
                    acc[mh * 4 + j][nt] = mfma16(af[j], bfr[nt], acc[mh * 4 + j][nt]);
            __builtin_amdgcn_s_setprio(0);
            if (q == 3 && t < 15)
                __builtin_amdgcn_s_waitcnt(WAITCNT_VM(0));  // tile t+1 landed
            __builtin_amdgcn_s_barrier();
        }
    }

    // ---- epilogue: Q/K scatter to [b,h,i,d]; V to permuted vtg ----
    int tensor = by >> 2;                    // 0=Q 1=K 2=V
    int nbase = (by & 3) * 256;
    const float* bias = tensor == 0 ? bq : tensor == 1 ? bk : bv;
    float scale = tensor == 0 ? QSCALE : 1.0f;
    if (tensor < 2) {
        unsigned short* outt = out_bf + (size_t)tensor * (32u * T_SEQ * DH);
        #pragma unroll
        for (int mt = 0; mt < 8; mt++) {
            #pragma unroll
            for (int nt = 0; nt < 4; nt++) {
                int n = nbase + wn_id * 64 + nt * 16 + lrow;     // n' = h*64+d
                int h = n >> 6, d = n & 63;
                float bb = bias[d * 16 + h];
                #pragma unroll
                for (int r = 0; r < 4; r++) {
                    int row = (int)am0 + wm_id * 128 + mt * 16 + lq * 4 + r;
                    float v = (acc[mt][nt][r] + bb) * scale;
                    int b = row >> 11, i = row & 2047;
                    long idx = ((long)(b * 16 + h) * T_SEQ + i) * DH + d;
                    outt[idx] = f32_bf16(v);
                }
            }
        }
    } else {
        int row0 = (int)am0 + wm_id * 128;           // multiple of 128
        int b = row0 >> 11;
        int blkb = (row0 & 2047) >> 6;
        // vtg j'-slot permutation (within each 64-token block): position
        // g*32 + lq*8 + nt'*4 + r holds token (g*2+nt')*16 + lq*4 + r.
        #pragma unroll
        for (int nt = 0; nt < 4; nt++) {
            int n = nbase + wn_id * 64 + nt * 16 + lrow;
            int h = n >> 6, d = n & 63;
            float bb = bias[d * 16 + h];
            #pragma unroll
            for (int mt = 0; mt < 8; mt++) {
                int blk = blkb + (mt >> 2);
                int m4 = mt & 3;
                long base = (((long)(b * 16 + h) * 64 + d) * 32 + blk) * 64;
                uint2 o;
                o.x = pack2_bf16(acc[mt][nt][0] + bb, acc[mt][nt][1] + bb);
                o.y = pack2_bf16(acc[mt][nt][2] + bb, acc[mt][nt][3] + bb);
                *(uint2*)(vtg + base + (m4 >> 1) * 32 + lq * 8 + (m4 & 1) * 4) = o;
            }
        }
    }
}

// ---------------- GEMM: C = A(bf16) @ W(bf16)^T, K = 1024 ----------------
// O-proj (grid 512): dbuf manual partial-vmcnt (48 KB, 2 blocks/CU).
// XOR-swizzled LDS (0 bank conflicts measured), XCD-aware block swizzle.
template <int BN, int MODE>
__global__ __launch_bounds__(256) void k_gemm(const unsigned short* __restrict__ A,
                                              const unsigned short* __restrict__ W,
                                              const float* __restrict__ b0,
                                              const float* __restrict__ resid,
                                              float* __restrict__ out_f32) {
    constexpr int NT = BN / 32;
    constexpr int NCB = BN / 32;
    constexpr int NDMA = 4 + NCB;            // DMA instrs per thread per stage
    __shared__ unsigned short lds_a[2 * 128 * 64];
    __shared__ unsigned short lds_b[2 * BN * 64];
    const int tid = threadIdx.x;
    const int w = tid >> 6, l = tid & 63;
    const int lrow = l & 15, lq = l >> 4;
    const int wm = (w >> 1) * 64, wn = (w & 1) * (BN / 2);
    const int L = blockIdx.x;
    const int bx = (L & 7) * 4 + ((L >> 3) & 3);
    const int by = L >> 5;
    const long am0 = (long)bx * 128;
    const long wn0 = (long)by * BN;

    floatx4 acc[4][NT] = {};
    const int grow = l >> 3;
    const int gcol = ((l & 7) ^ grow) * 8;   // column-group XOR swizzle (global side)
    const int sw8 = (lrow & 7);

    auto stage = [&](int ki, int sel) {
        unsigned short* la = lds_a + sel * 8192;
        unsigned short* lb = lds_b + sel * (BN * 64);
        int k0 = ki * 64;
        #pragma unroll
        for (int c = 0; c < 4; c++) {
            int chunk = w * 4 + c;
            gl2lds16(A + (am0 + chunk * 8 + grow) * D_MODEL + k0 + gcol, la + chunk * 512);
        }
        #pragma unroll
        for (int c = 0; c < NCB; c++) {
            int chunk = w * NCB + c;
            gl2lds16(W + (wn0 + chunk * 8 + grow) * D_MODEL + k0 + gcol, lb + chunk * 512);
        }
    };

    auto compute = [&](const unsigned short* la, const unsigned short* lb) {
        bf16x8 af[4][2], bfr[NT][2];
        #pragma unroll
        for (int mt = 0; mt < 4; mt++)
            #pragma unroll
            for (int ks = 0; ks < 2; ks++)
                af[mt][ks] = *(const bf16x8*)(la + (wm + mt * 16 + lrow) * 64 +
                                              (((ks * 4 + lq) ^ sw8) * 8));
        #pragma unroll
        for (int nt = 0; nt < NT; nt++)
            #pragma unroll
            for (int ks = 0; ks < 2; ks++)
                bfr[nt][ks] = *(const bf16x8*)(lb + (wn + nt * 16 + lrow) * 64 +
                                               (((ks * 4 + lq) ^ sw8) * 8));
        #pragma unroll
        for (int mt = 0; mt < 4; mt++)
            #pragma unroll
            for (int nt = 0; nt < NT; nt++)
                #pragma unroll
                for (int ks = 0; ks < 2; ks++)
                    acc[mt][nt] = mfma16(af[mt][ks], bfr[nt][ks], acc[mt][nt]);
    };

    stage(0, 0);
    for (int i = 0; i < 16; i++) {
        const int cur = i & 1;
        if (i < 15) {
            stage(i + 1, 1 - cur);
            __builtin_amdgcn_s_waitcnt(WAITCNT_VM(NDMA));  // drain stage(i), keep stage(i+1)
        } else {
            __builtin_amdgcn_s_waitcnt(WAITCNT_VM(0));
        }
        __builtin_amdgcn_s_barrier();
        compute(lds_a + cur * 8192, lds_b + cur * (BN * 64));
        __builtin_amdgcn_s_barrier();   // raw: reads of buf[cur] done before restage (i+2)
    }

    #pragma unroll
    for (int mt = 0; mt < 4; mt++) {
        #pragma unroll
        for (int nt = 0; nt < NT; nt++) {
            int n = (int)wn0 + wn + nt * 16 + lrow;
            float bb = b0[n];
            #pragma unroll
            for (int r = 0; r < 4; r++) {
                int row = (int)am0 + wm + mt * 16 + lq * 4 + r;
                long idx = (long)row * D_MODEL + n;
                out_f32[idx] = acc[mt][nt][r] + bb + resid[idx];
            }
        }
    }
}

// ---------------- attention: ring-4 LDS + single-barrier counted-vmcnt pipeline --------
// r13 = r11/B (measured best: 46.8us) + T5 setprio around the pure-MFMA
// l_acc+PV burst. B structure: ring of 4 K/V tile-slots (64 KB LDS), ONE
// barrier per tile, counted vmcnt with 2-tile flight (12 outstanding ->
// vmcnt(8) drains exactly S(t)); body = QK with sp4-of-prev-nt interleaved
// (TRANS under MFMA), then pack + l_acc + PV same-tile. setprio(1) during the
// 20-MFMA burst makes the CU scheduler favor this wave over the co-resident
// block's VALU-phase waves (m191 mechanism: blocks independently phased).
// Ring safety: stage S(t+2)->slot (t+2)&3 issued after passing barrier(t-1),
// all waves finished body t-2 (last reader); distance >= 2 mod 4.
__global__ __launch_bounds__(256) void k_attn(const unsigned short* __restrict__ q_ws,
                                              const unsigned short* __restrict__ k_ws,
                                              const unsigned short* __restrict__ vtg,
                                              unsigned short* __restrict__ att) {
    __shared__ unsigned short kbuf[4 * 4096];
    __shared__ unsigned short vbuf[4 * 4096];
    const int tid = threadIdx.x;
    const int w = tid >> 6, l = tid & 63;
    const int lrow = l & 15, lq = l >> 4;
    const int sw = lrow & 7;
    const int L = blockIdx.x;
    const int bh = (L & 7) * 4 + ((L >> 3) & 3);   // 4 bh per XCD -> K/V L2-resident
    const int i0 = (L >> 5) * 128;
    const unsigned short* kh = k_ws + (long)bh * T_SEQ * DH;
    const unsigned short* vh = vtg + (long)bh * 64 * T_SEQ;  // [d][blk][j'-permuted]

    const int rl = l >> 3;                     // staging: row within 8-row chunk
    const int gl = ((l & 7) ^ rl) * 8;         // staging: swizzled granule (shorts)

    bf16x8 qf[2][2];
    #pragma unroll
    for (int qt = 0; qt < 2; qt++) {
        const unsigned short* qp =
            q_ws + ((long)bh * T_SEQ + i0 + w * 32 + qt * 16 + lrow) * DH + lq * 8;
        qf[qt][0] = *(const bf16x8*)qp;
        qf[qt][1] = *(const bf16x8*)(qp + 32);
    }
    floatx4 o_acc[2][4] = {};
    floatx4 l_acc[2] = {};
    const short8v ones8s = {0x3F80, 0x3F80, 0x3F80, 0x3F80, 0x3F80, 0x3F80, 0x3F80, 0x3F80};
    const bf16x8 ones8 = as_bf(ones8s);

    // one K/V tile stage: 4 DMA instrs per thread (2 K + 2 V)
    auto stage = [&](int jt, int sel) {
        unsigned short* kd = kbuf + sel * 4096 + (w * 2) * 512;
        unsigned short* vd = vbuf + sel * 4096 + (w * 2) * 512;
        #pragma unroll
        for (int c = 0; c < 2; c++) {
            int row = w * 16 + c * 8 + rl;     // 0..63
            gl2lds16(kh + ((long)(jt * 64 + row)) * 64 + gl, kd + c * 512);
        }
        #pragma unroll
        for (int c = 0; c < 2; c++) {
            int row = w * 16 + c * 8 + rl;
            gl2lds16(vh + ((long)row * 32 + jt) * 64 + gl, vd + c * 512);
        }
    };

    // p = exp2(s); pack 4 bf16 (truncation via perm)
    auto sp4 = [&](floatx4 s) -> short4v {
        float p0 = __builtin_amdgcn_exp2f(s[0]);
        float p1 = __builtin_amdgcn_exp2f(s[1]);
        float p2 = __builtin_amdgcn_exp2f(s[2]);
        float p3 = __builtin_amdgcn_exp2f(s[3]);
        uint2 pk;
        pk.x = __builtin_amdgcn_perm(__float_as_uint(p1), __float_as_uint(p0), 0x07060302);
        pk.y = __builtin_amdgcn_perm(__float_as_uint(p3), __float_as_uint(p2), 0x07060302);
        union { uint2 u; short4v s4; } cv; cv.u = pk;
        return cv.s4;
    };

    // O^T += V^T * P for one dt, both q-tiles, K=32 (two j-halves g=0/1)
    auto pv_dt = [&](const unsigned short* vb_, int dt,
                     short8v (&p0)[2], short8v (&p1)[2]) {
        const unsigned short* vp = vb_ + (dt * 16 + lrow) * 64;
        bf16x8 vg0 = *(const bf16x8*)(vp + ((lq ^ sw) * 8));         // granule lq   (j 0..31)
        bf16x8 vg1 = *(const bf16x8*)(vp + (((4 + lq) ^ sw) * 8));   // granule 4+lq (j 32..63)
        o_acc[0][dt] = mfma16(vg0, as_bf(p0[0]), o_acc[0][dt]);
        o_acc[0][dt] = mfma16(vg1, as_bf(p0[1]), o_acc[0][dt]);
        o_acc[1][dt] = mfma16(vg0, as_bf(p1[0]), o_acc[1][dt]);
        o_acc[1][dt] = mfma16(vg1, as_bf(p1[1]), o_acc[1][dt]);
    };

    stage(0, 0);
    stage(1, 1);

    for (int t = 0; t < 32; t++) {
        const int sl = t & 3;
        if (t < 30) stage(t + 2, (t + 2) & 3);
        if (t < 30)
            __builtin_amdgcn_s_waitcnt(WAITCNT_VM(8));   // drain S(t), keep S(t+1),S(t+2)
        else if (t == 30)
            __builtin_amdgcn_s_waitcnt(WAITCNT_VM(4));   // drain S(30), keep S(31)
        else
            __builtin_amdgcn_s_waitcnt(WAITCNT_VM(0));   // drain S(31)
        __builtin_amdgcn_s_barrier();                    // all waves' S(t) landed

        const unsigned short* kb_ = kbuf + sl * 4096;
        const unsigned short* vb_ = vbuf + sl * 4096;

        // QK^T with sp4 of the previous nt-group interleaved (TRANS under MFMA)
        floatx4 s0[4], s1[4];
        short4v u0[4], u1[4];
        #pragma unroll
        for (int nt = 0; nt < 4; nt++) {
            const unsigned short* kp = kb_ + (nt * 16 + lrow) * 64;
            bf16x8 ka = *(const bf16x8*)(kp + ((lq ^ sw) * 8));
            bf16x8 kb2 = *(const bf16x8*)(kp + (((lq + 4) ^ sw) * 8));
            floatx4 c0 = {-EXP2_SHIFT, -EXP2_SHIFT, -EXP2_SHIFT, -EXP2_SHIFT};
            floatx4 c1 = c0;
            c0 = mfma16(ka, qf[0][0], c0);
            c0 = mfma16(kb2, qf[0][1], c0);
            c1 = mfma16(ka, qf[1][0], c1);
            c1 = mfma16(kb2, qf[1][1], c1);
            s0[nt] = c0;
            s1[nt] = c1;
            if (nt > 0) {
                u0[nt - 1] = sp4(s0[nt - 1]);
                u1[nt - 1] = sp4(s1[nt - 1]);
            }
        }
        u0[3] = sp4(s0[3]);
        u1[3] = sp4(s1[3]);
        short8v pf0[2], pf1[2];
        pf0[0] = __builtin_shufflevector(u0[0], u0[1], 0, 1, 2, 3, 4, 5, 6, 7);
        pf0[1] = __builtin_shufflevector(u0[2], u0[3], 0, 1, 2, 3, 4, 5, 6, 7);
        pf1[0] = __builtin_shufflevector(u1[0], u1[1], 0, 1, 2, 3, 4, 5, 6, 7);
        pf1[1] = __builtin_shufflevector(u1[2], u1[3], 0, 1, 2, 3, 4, 5, 6, 7);
        // pure-MFMA burst: l_acc (4) + PV (16) — boost arbitration priority
        __builtin_amdgcn_s_setprio(1);
        l_acc[0] = mfma16(ones8, as_bf(pf0[0]), l_acc[0]);
        l_acc[0] = mfma16(ones8, as_bf(pf0[1]), l_acc[0]);
        l_acc[1] = mfma16(ones8, as_bf(pf1[0]), l_acc[1]);
        l_acc[1] = mfma16(ones8, as_bf(pf1[1]), l_acc[1]);
        #pragma unroll
        for (int dt = 0; dt < 4; dt++) pv_dt(vb_, dt, pf0, pf1);
        __builtin_amdgcn_s_setprio(0);
        // no trailing barrier: ring-4 slot discipline covers restage safety
    }

    int h = bh & 15, b = bh >> 4;
    #pragma unroll
    for (int qt = 0; qt < 2; qt++) {
        float rl2 = 1.0f / l_acc[qt][0];
        int i = i0 + w * 32 + qt * 16 + lrow;
        unsigned short* orow = att + ((long)(b * T_SEQ + i)) * D_MODEL + h * 64;
        #pragma unroll
        for (int dt = 0; dt < 4; dt++) {
            uint2 o;
            o.x = pack2_bf16(o_acc[qt][dt][0] * rl2, o_acc[qt][dt][1] * rl2);
            o.y = pack2_bf16(o_acc[qt][dt][2] * rl2, o_acc[qt][dt][3] * rl2);
            *(uint2*)(orow + dt * 16 + lq * 4) = o;
        }
    }
}

// ---------------- LayerNorm in-place on d_out ----------------
__global__ __launch_bounds__(256) void k_ln(float* __restrict__ io,
                                            const float* __restrict__ gamma,
                                            const float* __restrict__ beta) {
    int row = blockIdx.x, t = threadIdx.x;
    float* p = io + (long)row * D_MODEL + t * 4;
    float4 v = *(float4*)p;
    float s = v.x + v.y + v.z + v.w;
    float ss = v.x * v.x + v.y * v.y + v.z * v.z + v.w * v.w;
    #pragma unroll
    for (int m = 1; m < 64; m <<= 1) {
        s += __shfl_xor(s, m);
        ss += __shfl_xor(ss, m);
    }
    __shared__ float red[8];
    if ((t & 63) == 0) { red[t >> 6] = s; red[4 + (t >> 6)] = ss; }
    __syncthreads();
    s = red[0] + red[1] + red[2] + red[3];
    ss = red[4] + red[5] + red[6] + red[7];
    float mu = s * (1.0f / 1024.0f);
    float var = ss * (1.0f / 1024.0f) - mu * mu;
    float rstd = rsqrtf(var + 1e-5f);
    float4 g = *(const float4*)(gamma + t * 4);
    float4 be = *(const float4*)(beta + t * 4);
    float4 o;
    o.x = (v.x - mu) * rstd * g.x + be.x;
    o.y = (v.y - mu) * rstd * g.y + be.y;
    o.z = (v.z - mu) * rstd * g.z + be.z;
    o.w = (v.w - mu) * rstd * g.w + be.w;
    *(float4*)p = o;
}

extern "C" void kernel_launch(void* const* d_in, const int* in_sizes, int n_in,
                              void* d_out, int out_size, void* d_ws, size_t ws_size,
                              hipStream_t stream) {
    const float* x = (const float*)d_in[0];
    const float* Wq = (const float*)d_in[1];
    const float* bq = (const float*)d_in[2];
    const float* Wk = (const float*)d_in[3];
    const float* bk = (const float*)d_in[4];
    const float* Wv = (const float*)d_in[5];
    const float* bv = (const float*)d_in[6];
    const float* Wo = (const float*)d_in[7];
    const float* bo = (const float*)d_in[8];
    const float* gamma = (const float*)d_in[9];
    const float* beta = (const float*)d_in[10];
    float* out = (float*)d_out;

    char* ws = (char*)d_ws;
    unsigned short* x_bf = (unsigned short*)(ws);                       // 0-8 MB (reused as att)
    unsigned short* wqkv_bf = (unsigned short*)(ws + ((size_t)8 << 20));// 8-14 MB
    unsigned short* wo_bf = (unsigned short*)(ws + ((size_t)14 << 20)); // 14-16 MB
    unsigned short* qkv_ws = (unsigned short*)(ws + ((size_t)16 << 20));// 16-40 MB (q|k|vt)
    unsigned short* att = x_bf;  // alias: x_bf dead after QKV GEMM

    unsigned short* q_ws = qkv_ws;
    unsigned short* k_ws = qkv_ws + (size_t)32 * T_SEQ * DH;
    unsigned short* vtg = qkv_ws + (size_t)64 * T_SEQ * DH;

    k_conv_all<<<8192, 256, 0, stream>>>(x, Wq, Wk, Wv, Wo, x_bf, wqkv_bf, wo_bf);

    // fused QKV GEMM: 256x256 tiles, N = 3072, grid 192 (XCD-chunked)
    k_qkv256<<<192, 512, 0, stream>>>(x_bf, wqkv_bf, bq, bk, bv, qkv_ws, vtg);

    k_attn<<<512, 256, 0, stream>>>(q_ws, k_ws, vtg, att);

    // O-projection + bias + residual: N = 1024, 1D grid with XCD swizzle
    k_gemm<64, 1><<<512, 256, 0, stream>>>(
        att, wo_bf, bo, x, out);

    k_ln<<<NROWS, 256, 0, stream>>>(out, gamma, beta);
}

// Round 8
// 191.503 us; speedup vs baseline: 1.0413x; 1.0192x over previous
//
#include <hip/hip_runtime.h>
#include <stdint.h>

#define T_SEQ 2048
#define D_MODEL 1024
#define NH 16
#define DH 64
#define NROWS 4096  // B*T

typedef __bf16 bf16x8 __attribute__((ext_vector_type(8)));
typedef float floatx4 __attribute__((ext_vector_type(4)));
typedef short short4v __attribute__((ext_vector_type(4)));
typedef short short8v __attribute__((ext_vector_type(8)));

#define AS1 __attribute__((address_space(1)))
#define AS3 __attribute__((address_space(3)))

static __device__ __forceinline__ void gl2lds16(const unsigned short* g, unsigned short* s) {
    __builtin_amdgcn_global_load_lds((const AS1 unsigned int*)g, (AS3 unsigned int*)s, 16, 0, 0);
}

static __device__ __forceinline__ unsigned short f32_bf16(float f) {
    union { float f; unsigned int u; } c; c.f = f;
    unsigned int u = c.u;
    u = u + 0x7FFFu + ((u >> 16) & 1u);   // RNE
    return (unsigned short)(u >> 16);
}

static __device__ __forceinline__ unsigned int pack2_bf16(float a, float b) {
    return (unsigned int)f32_bf16(a) | ((unsigned int)f32_bf16(b) << 16);
}

static __device__ __forceinline__ floatx4 mfma16(bf16x8 a, bf16x8 b, floatx4 c) {
    return __builtin_amdgcn_mfma_f32_16x16x32_bf16(a, b, c, 0, 0, 0);
}

static __device__ __forceinline__ bf16x8 as_bf(short8v s) {
    union { short8v s; bf16x8 b; } u; u.s = s; return u.b;
}

#define QSCALE 0.1803368801111204f   // (1/8) * log2(e); softmax in exp2 domain
#define EXP2_SHIFT 10.0f
// s_waitcnt imm: vmcnt[3:0], expcnt[6:4]=7 (nowait), lgkmcnt[11:8]=0xF (nowait)
#define WAITCNT_VM(n) (0x0F70 | (n))

// ---------------- fused conversion kernel ----------------
// r14: Wo branch reads float4 COALESCED and permutes via a 2KB LDS tile
// (old code gathered 4B at 64B stride -> ~16x line overfetch, latency-bound).
// dest f' = (f&15)*64 + (f>>4) is the exact inverse of the old per-dest gather
// src = (f'&63)*16 + (f'>>6) -> bitwise-identical wo_bf.
__global__ __launch_bounds__(256) void k_conv_all(const float* __restrict__ x,
                                                  const float* __restrict__ Wq,
                                                  const float* __restrict__ Wk,
                                                  const float* __restrict__ Wv,
                                                  const float* __restrict__ Wo,
                                                  unsigned short* __restrict__ x_bf,
                                                  unsigned short* __restrict__ wqkv_bf,
                                                  unsigned short* __restrict__ wo_bf) {
    __shared__ unsigned short lt[1024];
    int b = blockIdx.x, t = threadIdx.x;
    if (b < 4096) {
        int i = b * 1024 + t * 4;
        float4 v = *(const float4*)(x + i);
        uint2 o;
        o.x = pack2_bf16(v.x, v.y);
        o.y = pack2_bf16(v.z, v.w);
        *(uint2*)(x_bf + i) = o;
    } else if (b < 7168) {
        int idx = b - 4096;
        int tensor = idx >> 10, np = idx & 1023;
        const float* src = tensor == 0 ? Wq : tensor == 1 ? Wk : Wv;
        int f = (np & 63) * 16 + (np >> 6);
        int c = t * 4;
        float4 v = *(const float4*)(src + (long)f * D_MODEL + c);
        uint2 o;
        o.x = pack2_bf16(v.x, v.y);
        o.y = pack2_bf16(v.z, v.w);
        *(uint2*)(wqkv_bf + ((long)tensor * D_MODEL + np) * D_MODEL + c) = o;
    } else {
        int n = b - 7168;
        const float* row = Wo + (long)n * D_MODEL;
        float4 v = *(const float4*)(row + t * 4);
        {
            int f = t * 4;
            lt[((f + 0) & 15) * 64 + ((f + 0) >> 4)] = f32_bf16(v.x);
            lt[((f + 1) & 15) * 64 + ((f + 1) >> 4)] = f32_bf16(v.y);
            lt[((f + 2) & 15) * 64 + ((f + 2) >> 4)] = f32_bf16(v.z);
            lt[((f + 3) & 15) * 64 + ((f + 3) >> 4)] = f32_bf16(v.w);
        }
        __syncthreads();
        *(uint2*)(wo_bf + (long)n * D_MODEL + t * 4) = *(const uint2*)(lt + t * 4);
    }
}

// ---------------- QKV GEMM: 256x256 tile, 8-wave, 4-phase K-loop ----------------
// Stage pieces 3/3/2 over q0-q2 (measured-good in r4/r6). Grid 192 (16x12),
// XCD-chunked; 1 block/CU. (128 KB LDS -> ring-3 impossible here; frozen.)
__global__ __launch_bounds__(512, 2) void k_qkv256(const unsigned short* __restrict__ A,
                                                   const unsigned short* __restrict__ W,
                                                   const float* __restrict__ bq,
                                                   const float* __restrict__ bk,
                                                   const float* __restrict__ bv,
                                                   unsigned short* __restrict__ out_bf,
                                                   unsigned short* __restrict__ vtg) {
    __shared__ unsigned short lds[2 * 32768];   // buf: A[256][64] | B[256][64]
    const int tid = threadIdx.x;
    const int w = tid >> 6, l = tid & 63;
    const int lrow = l & 15, lq = l >> 4;
    const int sw8 = lrow & 7;
    const int wm_id = w >> 2, wn_id = w & 3;
    const int L = blockIdx.x;
    const int bx = (L & 7) * 2 + ((L >> 3) & 1);
    const int by = L >> 4;                       // 0..11
    const long am0 = (long)bx * 256;
    const long wn0 = (long)by * 256;

    const int rl = l >> 3;                       // staging: row within 8-row chunk
    const int gl = ((l & 7) ^ rl) * 8;           // staging: swizzled granule (shorts)

    floatx4 acc[8][4] = {};

    // piece 0..3: A chunks; 4..7: B chunks. 1 DMA instr/thread/piece.
    auto stage_piece = [&](int ki, int sel, int piece) {
        int c = piece & 3;
        int chunk = c * 8 + w;                   // 0..31 (8 rows each)
        int k0 = ki * 64;
        if (piece < 4) {
            gl2lds16(A + (am0 + chunk * 8 + rl) * D_MODEL + k0 + gl,
                     lds + sel * 32768 + chunk * 512);
        } else {
            gl2lds16(W + (wn0 + chunk * 8 + rl) * D_MODEL + k0 + gl,
                     lds + sel * 32768 + 16384 + chunk * 512);
        }
    };

    // prologue: tile 0 fully staged
    #pragma unroll
    for (int pc = 0; pc < 8; pc++) stage_piece(0, 0, pc);
    __builtin_amdgcn_s_waitcnt(WAITCNT_VM(0));
    __builtin_amdgcn_s_barrier();

    for (int t = 0; t < 16; t++) {
        const int sel = t & 1;
        const unsigned short* Ab = lds + sel * 32768;
        const unsigned short* Bb = Ab + 16384;
        bf16x8 bfr[4];
        #pragma unroll
        for (int q = 0; q < 4; q++) {
            const int ks = q >> 1, mh = q & 1;
            if (mh == 0) {
                #pragma unroll
                for (int nt = 0; nt < 4; nt++) {
                    int row = wn_id * 64 + nt * 16 + lrow;
                    bfr[nt] = *(const bf16x8*)(Bb + row * 64 + (((ks * 4 + lq) ^ sw8) * 8));
                }
            }
            bf16x8 af[4];
            #pragma unroll
            for (int j = 0; j < 4; j++) {
                int row = wm_id * 128 + (mh * 4 + j) * 16 + lrow;
                af[j] = *(const bf16x8*)(Ab + row * 64 + (((ks * 4 + lq) ^ sw8) * 8));
            }
            if (t < 15) {
                // front-loaded: 3,3,2,0 pieces over q=0..3
                if (q == 0) {
                    stage_piece(t + 1, sel ^ 1, 0);
                    stage_piece(t + 1, sel ^ 1, 1);
                    stage_piece(t + 1, sel ^ 1, 2);
                } else if (q == 1) {
                    stage_piece(t + 1, sel ^ 1, 3);
                    stage_piece(t + 1, sel ^ 1, 4);
                    stage_piece(t + 1, sel ^ 1, 5);
                } else if (q == 2) {
                    stage_piece(t + 1, sel ^ 1, 6);
                    stage_piece(t + 1, sel ^ 1, 7);
                }
            }
            __builtin_amdgcn_s_barrier();
            __builtin_amdgcn_s_setprio(1);
            #pragma unroll
            for (int j = 0; j < 4; j++)
                #pragma unroll
                for (int nt = 0; nt < 4; nt++)
                    acc[mh * 4 + j][nt] = mfma16(af[j], bfr[nt], acc[mh * 4 + j][nt]);
            __builtin_amdgcn_s_setprio(0);
            if (q == 3 && t < 15)
                __builtin_amdgcn_s_waitcnt(WAITCNT_VM(0));  // tile t+1 landed
            __builtin_amdgcn_s_barrier();
        }
    }

    // ---- epilogue: Q/K scatter to [b,h,i,d]; V to permuted vtg ----
    int tensor = by >> 2;                    // 0=Q 1=K 2=V
    int nbase = (by & 3) * 256;
    const float* bias = tensor == 0 ? bq : tensor == 1 ? bk : bv;
    float scale = tensor == 0 ? QSCALE : 1.0f;
    if (tensor < 2) {
        unsigned short* outt = out_bf + (size_t)tensor * (32u * T_SEQ * DH);
        #pragma unroll
        for (int mt = 0; mt < 8; mt++) {
            #pragma unroll
            for (int nt = 0; nt < 4; nt++) {
                int n = nbase + wn_id * 64 + nt * 16 + lrow;     // n' = h*64+d
                int h = n >> 6, d = n & 63;
                float bb = bias[d * 16 + h];
                #pragma unroll
                for (int r = 0; r < 4; r++) {
                    int row = (int)am0 + wm_id * 128 + mt * 16 + lq * 4 + r;
                    float v = (acc[mt][nt][r] + bb) * scale;
                    int b = row >> 11, i = row & 2047;
                    long idx = ((long)(b * 16 + h) * T_SEQ + i) * DH + d;
                    outt[idx] = f32_bf16(v);
                }
            }
        }
    } else {
        int row0 = (int)am0 + wm_id * 128;           // multiple of 128
        int b = row0 >> 11;
        int blkb = (row0 & 2047) >> 6;
        // vtg j'-slot permutation (within each 64-token block): position
        // g*32 + lq*8 + nt'*4 + r holds token (g*2+nt')*16 + lq*4 + r.
        #pragma unroll
        for (int nt = 0; nt < 4; nt++) {
            int n = nbase + wn_id * 64 + nt * 16 + lrow;
            int h = n >> 6, d = n & 63;
            float bb = bias[d * 16 + h];
            #pragma unroll
            for (int mt = 0; mt < 8; mt++) {
                int blk = blkb + (mt >> 2);
                int m4 = mt & 3;
                long base = (((long)(b * 16 + h) * 64 + d) * 32 + blk) * 64;
                uint2 o;
                o.x = pack2_bf16(acc[mt][nt][0] + bb, acc[mt][nt][1] + bb);
                o.y = pack2_bf16(acc[mt][nt][2] + bb, acc[mt][nt][3] + bb);
                *(uint2*)(vtg + base + (m4 >> 1) * 32 + lq * 8 + (m4 & 1) * 4) = o;
            }
        }
    }
}

// ---------------- O-proj GEMM: C = A(bf16) @ W(bf16)^T, K = 1024 ----------------
// r14: ring-3 LDS (72 KB, still 2 blocks/CU) with 2-tile prefetch depth.
// Old dbuf gave S(i) only ~1 iteration (~500-700 cyc) of flight < ~900 cyc HBM
// latency -> per-iteration drain stall. Ring-3: stage(i+2) after the trailing
// barrier (slot (i+2)%3 == (i-1)%3, certified free by that barrier); steady
// outstanding = 18 DMAs -> vmcnt(12) drains exactly S(i) (2 iters of flight);
// tails vmcnt(6)/vmcnt(0).
template <int BN, int MODE>
__global__ __launch_bounds__(256) void k_gemm(const unsigned short* __restrict__ A,
                                              const unsigned short* __restrict__ W,
                                              const float* __restrict__ b0,
                                              const float* __restrict__ resid,
                                              float* __restrict__ out_f32) {
    constexpr int NT = BN / 32;
    constexpr int NCB = BN / 32;
    __shared__ unsigned short lds_a[3 * 128 * 64];
    __shared__ unsigned short lds_b[3 * BN * 64];
    const int tid = threadIdx.x;
    const int w = tid >> 6, l = tid & 63;
    const int lrow = l & 15, lq = l >> 4;
    const int wm = (w >> 1) * 64, wn = (w & 1) * (BN / 2);
    const int L = blockIdx.x;
    const int bx = (L & 7) * 4 + ((L >> 3) & 3);
    const int by = L >> 5;
    const long am0 = (long)bx * 128;
    const long wn0 = (long)by * BN;

    floatx4 acc[4][NT] = {};
    const int grow = l >> 3;
    const int gcol = ((l & 7) ^ grow) * 8;   // column-group XOR swizzle (global side)
    const int sw8 = (lrow & 7);

    auto stage = [&](int ki, int sel) {
        unsigned short* la = lds_a + sel * 8192;
        unsigned short* lb = lds_b + sel * (BN * 64);
        int k0 = ki * 64;
        #pragma unroll
        for (int c = 0; c < 4; c++) {
            int chunk = w * 4 + c;
            gl2lds16(A + (am0 + chunk * 8 + grow) * D_MODEL + k0 + gcol, la + chunk * 512);
        }
        #pragma unroll
        for (int c = 0; c < NCB; c++) {
            int chunk = w * NCB + c;
            gl2lds16(W + (wn0 + chunk * 8 + grow) * D_MODEL + k0 + gcol, lb + chunk * 512);
        }
    };

    auto compute = [&](const unsigned short* la, const unsigned short* lb) {
        bf16x8 af[4][2], bfr[NT][2];
        #pragma unroll
        for (int mt = 0; mt < 4; mt++)
            #pragma unroll
            for (int ks = 0; ks < 2; ks++)
                af[mt][ks] = *(const bf16x8*)(la + (wm + mt * 16 + lrow) * 64 +
                                              (((ks * 4 + lq) ^ sw8) * 8));
        #pragma unroll
        for (int nt = 0; nt < NT; nt++)
            #pragma unroll
            for (int ks = 0; ks < 2; ks++)
                bfr[nt][ks] = *(const bf16x8*)(lb + (wn + nt * 16 + lrow) * 64 +
                                               (((ks * 4 + lq) ^ sw8) * 8));
        #pragma unroll
        for (int mt = 0; mt < 4; mt++)
            #pragma unroll
            for (int nt = 0; nt < NT; nt++)
                #pragma unroll
                for (int ks = 0; ks < 2; ks++)
                    acc[mt][nt] = mfma16(af[mt][ks], bfr[nt][ks], acc[mt][nt]);
    };

    stage(0, 0);
    stage(1, 1);
    for (int i = 0; i < 16; i++) {
        const int sel = i % 3;
        if (i < 14) {
            stage(i + 2, (i + 2) % 3);
            __builtin_amdgcn_s_waitcnt(WAITCNT_VM(12));  // drain S(i), keep S(i+1),S(i+2)
        } else if (i == 14) {
            __builtin_amdgcn_s_waitcnt(WAITCNT_VM(6));   // drain S(14), keep S(15)
        } else {
            __builtin_amdgcn_s_waitcnt(WAITCNT_VM(0));   // drain S(15)
        }
        __builtin_amdgcn_s_barrier();
        compute(lds_a + sel * 8192, lds_b + sel * (BN * 64));
        __builtin_amdgcn_s_barrier();   // certifies compute(i) done -> slot i%3 reusable by S(i+3)
    }

    #pragma unroll
    for (int mt = 0; mt < 4; mt++) {
        #pragma unroll
        for (int nt = 0; nt < NT; nt++) {
            int n = (int)wn0 + wn + nt * 16 + lrow;
            float bb = b0[n];
            #pragma unroll
            for (int r = 0; r < 4; r++) {
                int row = (int)am0 + wm + mt * 16 + lq * 4 + r;
                long idx = (long)row * D_MODEL + n;
                out_f32[idx] = acc[mt][nt][r] + bb + resid[idx];
            }
        }
    }
}

// ---------------- attention: ring-4 LDS + single-barrier counted-vmcnt pipeline --------
// r13 structure (measured best: 44.0us): ring of 4 K/V tile-slots (64 KB LDS),
// ONE barrier per tile, counted vmcnt with 2-tile flight, sp4-of-prev-nt
// interleaved under QK MFMAs, setprio(1) around the pure-MFMA l_acc+PV burst.
// FROZEN this round.
__global__ __launch_bounds__(256) void k_attn(const unsigned short* __restrict__ q_ws,
                                              const unsigned short* __restrict__ k_ws,
                                              const unsigned short* __restrict__ vtg,
                                              unsigned short* __restrict__ att) {
    __shared__ unsigned short kbuf[4 * 4096];
    __shared__ unsigned short vbuf[4 * 4096];
    const int tid = threadIdx.x;
    const int w = tid >> 6, l = tid & 63;
    const int lrow = l & 15, lq = l >> 4;
    const int sw = lrow & 7;
    const int L = blockIdx.x;
    const int bh = (L & 7) * 4 + ((L >> 3) & 3);   // 4 bh per XCD -> K/V L2-resident
    const int i0 = (L >> 5) * 128;
    const unsigned short* kh = k_ws + (long)bh * T_SEQ * DH;
    const unsigned short* vh = vtg + (long)bh * 64 * T_SEQ;  // [d][blk][j'-permuted]

    const int rl = l >> 3;                     // staging: row within 8-row chunk
    const int gl = ((l & 7) ^ rl) * 8;         // staging: swizzled granule (shorts)

    bf16x8 qf[2][2];
    #pragma unroll
    for (int qt = 0; qt < 2; qt++) {
        const unsigned short* qp =
            q_ws + ((long)bh * T_SEQ + i0 + w * 32 + qt * 16 + lrow) * DH + lq * 8;
        qf[qt][0] = *(const bf16x8*)qp;
        qf[qt][1] = *(const bf16x8*)(qp + 32);
    }
    floatx4 o_acc[2][4] = {};
    floatx4 l_acc[2] = {};
    const short8v ones8s = {0x3F80, 0x3F80, 0x3F80, 0x3F80, 0x3F80, 0x3F80, 0x3F80, 0x3F80};
    const bf16x8 ones8 = as_bf(ones8s);

    // one K/V tile stage: 4 DMA instrs per thread (2 K + 2 V)
    auto stage = [&](int jt, int sel) {
        unsigned short* kd = kbuf + sel * 4096 + (w * 2) * 512;
        unsigned short* vd = vbuf + sel * 4096 + (w * 2) * 512;
        #pragma unroll
        for (int c = 0; c < 2; c++) {
            int row = w * 16 + c * 8 + rl;     // 0..63
            gl2lds16(kh + ((long)(jt * 64 + row)) * 64 + gl, kd + c * 512);
        }
        #pragma unroll
        for (int c = 0; c < 2; c++) {
            int row = w * 16 + c * 8 + rl;
            gl2lds16(vh + ((long)row * 32 + jt) * 64 + gl, vd + c * 512);
        }
    };

    // p = exp2(s); pack 4 bf16 (truncation via perm)
    auto sp4 = [&](floatx4 s) -> short4v {
        float p0 = __builtin_amdgcn_exp2f(s[0]);
        float p1 = __builtin_amdgcn_exp2f(s[1]);
        float p2 = __builtin_amdgcn_exp2f(s[2]);
        float p3 = __builtin_amdgcn_exp2f(s[3]);
        uint2 pk;
        pk.x = __builtin_amdgcn_perm(__float_as_uint(p1), __float_as_uint(p0), 0x07060302);
        pk.y = __builtin_amdgcn_perm(__float_as_uint(p3), __float_as_uint(p2), 0x07060302);
        union { uint2 u; short4v s4; } cv; cv.u = pk;
        return cv.s4;
    };

    // O^T += V^T * P for one dt, both q-tiles, K=32 (two j-halves g=0/1)
    auto pv_dt = [&](const unsigned short* vb_, int dt,
                     short8v (&p0)[2], short8v (&p1)[2]) {
        const unsigned short* vp = vb_ + (dt * 16 + lrow) * 64;
        bf16x8 vg0 = *(const bf16x8*)(vp + ((lq ^ sw) * 8));         // granule lq   (j 0..31)
        bf16x8 vg1 = *(const bf16x8*)(vp + (((4 + lq) ^ sw) * 8));   // granule 4+lq (j 32..63)
        o_acc[0][dt] = mfma16(vg0, as_bf(p0[0]), o_acc[0][dt]);
        o_acc[0][dt] = mfma16(vg1, as_bf(p0[1]), o_acc[0][dt]);
        o_acc[1][dt] = mfma16(vg0, as_bf(p1[0]), o_acc[1][dt]);
        o_acc[1][dt] = mfma16(vg1, as_bf(p1[1]), o_acc[1][dt]);
    };

    stage(0, 0);
    stage(1, 1);

    for (int t = 0; t < 32; t++) {
        const int sl = t & 3;
        if (t < 30) stage(t + 2, (t + 2) & 3);
        if (t < 30)
            __builtin_amdgcn_s_waitcnt(WAITCNT_VM(8));   // drain S(t), keep S(t+1),S(t+2)
        else if (t == 30)
            __builtin_amdgcn_s_waitcnt(WAITCNT_VM(4));   // drain S(30), keep S(31)
        else
            __builtin_amdgcn_s_waitcnt(WAITCNT_VM(0));   // drain S(31)
        __builtin_amdgcn_s_barrier();                    // all waves' S(t) landed

        const unsigned short* kb_ = kbuf + sl * 4096;
        const unsigned short* vb_ = vbuf + sl * 4096;

        // QK^T with sp4 of the previous nt-group interleaved (TRANS under MFMA)
        floatx4 s0[4], s1[4];
        short4v u0[4], u1[4];
        #pragma unroll
        for (int nt = 0; nt < 4; nt++) {
            const unsigned short* kp = kb_ + (nt * 16 + lrow) * 64;
            bf16x8 ka = *(const bf16x8*)(kp + ((lq ^ sw) * 8));
            bf16x8 kb2 = *(const bf16x8*)(kp + (((lq + 4) ^ sw) * 8));
            floatx4 c0 = {-EXP2_SHIFT, -EXP2_SHIFT, -EXP2_SHIFT, -EXP2_SHIFT};
            floatx4 c1 = c0;
            c0 = mfma16(ka, qf[0][0], c0);
            c0 = mfma16(kb2, qf[0][1], c0);
            c1 = mfma16(ka, qf[1][0], c1);
            c1 = mfma16(kb2, qf[1][1], c1);
            s0[nt] = c0;
            s1[nt] = c1;
            if (nt > 0) {
                u0[nt - 1] = sp4(s0[nt - 1]);
                u1[nt - 1] = sp4(s1[nt - 1]);
            }
        }
        u0[3] = sp4(s0[3]);
        u1[3] = sp4(s1[3]);
        short8v pf0[2], pf1[2];
        pf0[0] = __builtin_shufflevector(u0[0], u0[1], 0, 1, 2, 3, 4, 5, 6, 7);
        pf0[1] = __builtin_shufflevector(u0[2], u0[3], 0, 1, 2, 3, 4, 5, 6, 7);
        pf1[0] = __builtin_shufflevector(u1[0], u1[1], 0, 1, 2, 3, 4, 5, 6, 7);
        pf1[1] = __builtin_shufflevector(u1[2], u1[3], 0, 1, 2, 3, 4, 5, 6, 7);
        // pure-MFMA burst: l_acc (4) + PV (16) — boost arbitration priority
        __builtin_amdgcn_s_setprio(1);
        l_acc[0] = mfma16(ones8, as_bf(pf0[0]), l_acc[0]);
        l_acc[0] = mfma16(ones8, as_bf(pf0[1]), l_acc[0]);
        l_acc[1] = mfma16(ones8, as_bf(pf1[0]), l_acc[1]);
        l_acc[1] = mfma16(ones8, as_bf(pf1[1]), l_acc[1]);
        #pragma unroll
        for (int dt = 0; dt < 4; dt++) pv_dt(vb_, dt, pf0, pf1);
        __builtin_amdgcn_s_setprio(0);
        // no trailing barrier: ring-4 slot discipline covers restage safety
    }

    int h = bh & 15, b = bh >> 4;
    #pragma unroll
    for (int qt = 0; qt < 2; qt++) {
        float rl2 = 1.0f / l_acc[qt][0];
        int i = i0 + w * 32 + qt * 16 + lrow;
        unsigned short* orow = att + ((long)(b * T_SEQ + i)) * D_MODEL + h * 64;
        #pragma unroll
        for (int dt = 0; dt < 4; dt++) {
            uint2 o;
            o.x = pack2_bf16(o_acc[qt][dt][0] * rl2, o_acc[qt][dt][1] * rl2);
            o.y = pack2_bf16(o_acc[qt][dt][2] * rl2, o_acc[qt][dt][3] * rl2);
            *(uint2*)(orow + dt * 16 + lq * 4) = o;
        }
    }
}

// ---------------- LayerNorm in-place on d_out ----------------
__global__ __launch_bounds__(256) void k_ln(float* __restrict__ io,
                                            const float* __restrict__ gamma,
                                            const float* __restrict__ beta) {
    int row = blockIdx.x, t = threadIdx.x;
    float* p = io + (long)row * D_MODEL + t * 4;
    float4 v = *(float4*)p;
    float s = v.x + v.y + v.z + v.w;
    float ss = v.x * v.x + v.y * v.y + v.z * v.z + v.w * v.w;
    #pragma unroll
    for (int m = 1; m < 64; m <<= 1) {
        s += __shfl_xor(s, m);
        ss += __shfl_xor(ss, m);
    }
    __shared__ float red[8];
    if ((t & 63) == 0) { red[t >> 6] = s; red[4 + (t >> 6)] = ss; }
    __syncthreads();
    s = red[0] + red[1] + red[2] + red[3];
    ss = red[4] + red[5] + red[6] + red[7];
    float mu = s * (1.0f / 1024.0f);
    float var = ss * (1.0f / 1024.0f) - mu * mu;
    float rstd = rsqrtf(var + 1e-5f);
    float4 g = *(const float4*)(gamma + t * 4);
    float4 be = *(const float4*)(beta + t * 4);
    float4 o;
    o.x = (v.x - mu) * rstd * g.x + be.x;
    o.y = (v.y - mu) * rstd * g.y + be.y;
    o.z = (v.z - mu) * rstd * g.z + be.z;
    o.w = (v.w - mu) * rstd * g.w + be.w;
    *(float4*)p = o;
}

extern "C" void kernel_launch(void* const* d_in, const int* in_sizes, int n_in,
                              void* d_out, int out_size, void* d_ws, size_t ws_size,
                              hipStream_t stream) {
    const float* x = (const float*)d_in[0];
    const float* Wq = (const float*)d_in[1];
    const float* bq = (const float*)d_in[2];
    const float* Wk = (const float*)d_in[3];
    const float* bk = (const float*)d_in[4];
    const float* Wv = (const float*)d_in[5];
    const float* bv = (const float*)d_in[6];
    const float* Wo = (const float*)d_in[7];
    const float* bo = (const float*)d_in[8];
    const float* gamma = (const float*)d_in[9];
    const float* beta = (const float*)d_in[10];
    float* out = (float*)d_out;

    char* ws = (char*)d_ws;
    unsigned short* x_bf = (unsigned short*)(ws);                       // 0-8 MB (reused as att)
    unsigned short* wqkv_bf = (unsigned short*)(ws + ((size_t)8 << 20));// 8-14 MB
    unsigned short* wo_bf = (unsigned short*)(ws + ((size_t)14 << 20)); // 14-16 MB
    unsigned short* qkv_ws = (unsigned short*)(ws + ((size_t)16 << 20));// 16-40 MB (q|k|vt)
    unsigned short* att = x_bf;  // alias: x_bf dead after QKV GEMM

    unsigned short* q_ws = qkv_ws;
    unsigned short* k_ws = qkv_ws + (size_t)32 * T_SEQ * DH;
    unsigned short* vtg = qkv_ws + (size_t)64 * T_SEQ * DH;

    k_conv_all<<<8192, 256, 0, stream>>>(x, Wq, Wk, Wv, Wo, x_bf, wqkv_bf, wo_bf);

    // fused QKV GEMM: 256x256 tiles, N = 3072, grid 192 (XCD-chunked)
    k_qkv256<<<192, 512, 0, stream>>>(x_bf, wqkv_bf, bq, bk, bv, qkv_ws, vtg);

    k_attn<<<512, 256, 0, stream>>>(q_ws, k_ws, vtg, att);

    // O-projection + bias + residual: N = 1024, 1D grid with XCD swizzle
    k_gemm<64, 1><<<512, 256, 0, stream>>>(
        att, wo_bf, bo, x, out);

    k_ln<<<NROWS, 256, 0, stream>>>(out, gamma, beta);
}

// Round 9
// 183.969 us; speedup vs baseline: 1.0840x; 1.0409x over previous
//
#include <hip/hip_runtime.h>
#include <stdint.h>

#define T_SEQ 2048
#define D_MODEL 1024
#define NH 16
#define DH 64
#define NROWS 4096  // B*T

typedef __bf16 bf16x8 __attribute__((ext_vector_type(8)));
typedef float floatx4 __attribute__((ext_vector_type(4)));
typedef short short4v __attribute__((ext_vector_type(4)));
typedef short short8v __attribute__((ext_vector_type(8)));

#define AS1 __attribute__((address_space(1)))
#define AS3 __attribute__((address_space(3)))

static __device__ __forceinline__ void gl2lds16(const unsigned short* g, unsigned short* s) {
    __builtin_amdgcn_global_load_lds((const AS1 unsigned int*)g, (AS3 unsigned int*)s, 16, 0, 0);
}

static __device__ __forceinline__ unsigned short f32_bf16(float f) {
    union { float f; unsigned int u; } c; c.f = f;
    unsigned int u = c.u;
    u = u + 0x7FFFu + ((u >> 16) & 1u);   // RNE
    return (unsigned short)(u >> 16);
}

static __device__ __forceinline__ unsigned int pack2_bf16(float a, float b) {
    return (unsigned int)f32_bf16(a) | ((unsigned int)f32_bf16(b) << 16);
}

static __device__ __forceinline__ floatx4 mfma16(bf16x8 a, bf16x8 b, floatx4 c) {
    return __builtin_amdgcn_mfma_f32_16x16x32_bf16(a, b, c, 0, 0, 0);
}

static __device__ __forceinline__ bf16x8 as_bf(short8v s) {
    union { short8v s; bf16x8 b; } u; u.s = s; return u.b;
}

#define QSCALE 0.1803368801111204f   // (1/8) * log2(e); softmax in exp2 domain
#define EXP2_SHIFT 10.0f
// s_waitcnt imm: vmcnt[3:0], expcnt[6:4]=7 (nowait), lgkmcnt[11:8]=0xF (nowait)
#define WAITCNT_VM(n) (0x0F70 | (n))

// ---------------- fused conversion kernel ----------------
// Wo branch reads float4 coalesced and permutes via a 2KB LDS tile (r14).
__global__ __launch_bounds__(256) void k_conv_all(const float* __restrict__ x,
                                                  const float* __restrict__ Wq,
                                                  const float* __restrict__ Wk,
                                                  const float* __restrict__ Wv,
                                                  const float* __restrict__ Wo,
                                                  unsigned short* __restrict__ x_bf,
                                                  unsigned short* __restrict__ wqkv_bf,
                                                  unsigned short* __restrict__ wo_bf) {
    __shared__ unsigned short lt[1024];
    int b = blockIdx.x, t = threadIdx.x;
    if (b < 4096) {
        int i = b * 1024 + t * 4;
        float4 v = *(const float4*)(x + i);
        uint2 o;
        o.x = pack2_bf16(v.x, v.y);
        o.y = pack2_bf16(v.z, v.w);
        *(uint2*)(x_bf + i) = o;
    } else if (b < 7168) {
        int idx = b - 4096;
        int tensor = idx >> 10, np = idx & 1023;
        const float* src = tensor == 0 ? Wq : tensor == 1 ? Wk : Wv;
        int f = (np & 63) * 16 + (np >> 6);
        int c = t * 4;
        float4 v = *(const float4*)(src + (long)f * D_MODEL + c);
        uint2 o;
        o.x = pack2_bf16(v.x, v.y);
        o.y = pack2_bf16(v.z, v.w);
        *(uint2*)(wqkv_bf + ((long)tensor * D_MODEL + np) * D_MODEL + c) = o;
    } else {
        int n = b - 7168;
        const float* row = Wo + (long)n * D_MODEL;
        float4 v = *(const float4*)(row + t * 4);
        {
            int f = t * 4;
            lt[((f + 0) & 15) * 64 + ((f + 0) >> 4)] = f32_bf16(v.x);
            lt[((f + 1) & 15) * 64 + ((f + 1) >> 4)] = f32_bf16(v.y);
            lt[((f + 2) & 15) * 64 + ((f + 2) >> 4)] = f32_bf16(v.z);
            lt[((f + 3) & 15) * 64 + ((f + 3) >> 4)] = f32_bf16(v.w);
        }
        __syncthreads();
        *(uint2*)(wo_bf + (long)n * D_MODEL + t * 4) = *(const uint2*)(lt + t * 4);
    }
}

// ---------------- QKV GEMM: 256x192 tile, 8-wave, 4-phase K-loop ----------------
// r15: re-tile N 256->192 so grid = 16x16 = 256 blocks = 1 block on EVERY CU
// (the 256x256 tiling's grid of 192 left 64 CUs idle -> 25% of the machine
// wasted; counters showed per-CU schedule healthy, coverage was the loss).
// 192-wide N-tiles straddle Q/K/V boundaries -> tensor dispatch moved to
// per-nt (16-wide nt-tiles lie wholly in one tensor; branch wave-uniform).
// LDS 2x(32K A + 24K B) = 112 KB. 7 stage pieces (4 A + 3 B) spread 3/3/1.
// K-loop accumulation order unchanged -> bitwise-identical output.
__global__ __launch_bounds__(512, 2) void k_qkv256(const unsigned short* __restrict__ A,
                                                   const unsigned short* __restrict__ W,
                                                   const float* __restrict__ bq,
                                                   const float* __restrict__ bk,
                                                   const float* __restrict__ bv,
                                                   unsigned short* __restrict__ out_bf,
                                                   unsigned short* __restrict__ vtg) {
    __shared__ unsigned short lds[2 * 28672];   // buf: A[256][64] | B[192][64]
    const int tid = threadIdx.x;
    const int w = tid >> 6, l = tid & 63;
    const int lrow = l & 15, lq = l >> 4;
    const int sw8 = lrow & 7;
    const int wm_id = w >> 2, wn_id = w & 3;
    const int L = blockIdx.x;
    const int bx = (L & 7) * 2 + ((L >> 3) & 1);   // 0..15
    const int by = L >> 4;                          // 0..15
    const long am0 = (long)bx * 256;
    const long wn0 = (long)by * 192;

    const int rl = l >> 3;                       // staging: row within 8-row chunk
    const int gl = ((l & 7) ^ rl) * 8;           // staging: swizzled granule (shorts)

    floatx4 acc[8][3] = {};

    // piece 0..3: A chunks; 4..6: B chunks. 1 DMA instr/thread/piece.
    auto stage_piece = [&](int ki, int sel, int piece) {
        int k0 = ki * 64;
        if (piece < 4) {
            int chunk = piece * 8 + w;           // 0..31 (8 rows each, 256 rows)
            gl2lds16(A + (am0 + chunk * 8 + rl) * D_MODEL + k0 + gl,
                     lds + sel * 28672 + chunk * 512);
        } else {
            int chunk = (piece - 4) * 8 + w;     // 0..23 (8 rows each, 192 rows)
            gl2lds16(W + (wn0 + chunk * 8 + rl) * D_MODEL + k0 + gl,
                     lds + sel * 28672 + 16384 + chunk * 512);
        }
    };

    // prologue: tile 0 fully staged
    #pragma unroll
    for (int pc = 0; pc < 7; pc++) stage_piece(0, 0, pc);
    __builtin_amdgcn_s_waitcnt(WAITCNT_VM(0));
    __builtin_amdgcn_s_barrier();

    for (int t = 0; t < 16; t++) {
        const int sel = t & 1;
        const unsigned short* Ab = lds + sel * 28672;
        const unsigned short* Bb = Ab + 16384;
        bf16x8 bfr[3];
        #pragma unroll
        for (int q = 0; q < 4; q++) {
            const int ks = q >> 1, mh = q & 1;
            if (mh == 0) {
                #pragma unroll
                for (int nt = 0; nt < 3; nt++) {
                    int row = wn_id * 48 + nt * 16 + lrow;
                    bfr[nt] = *(const bf16x8*)(Bb + row * 64 + (((ks * 4 + lq) ^ sw8) * 8));
                }
            }
            bf16x8 af[4];
            #pragma unroll
            for (int j = 0; j < 4; j++) {
                int row = wm_id * 128 + (mh * 4 + j) * 16 + lrow;
                af[j] = *(const bf16x8*)(Ab + row * 64 + (((ks * 4 + lq) ^ sw8) * 8));
            }
            if (t < 15) {
                // front-loaded: 3,3,1 pieces over q=0..2
                if (q == 0) {
                    stage_piece(t + 1, sel ^ 1, 0);
                    stage_piece(t + 1, sel ^ 1, 1);
                    stage_piece(t + 1, sel ^ 1, 2);
                } else if (q == 1) {
                    stage_piece(t + 1, sel ^ 1, 3);
                    stage_piece(t + 1, sel ^ 1, 4);
                    stage_piece(t + 1, sel ^ 1, 5);
                } else if (q == 2) {
                    stage_piece(t + 1, sel ^ 1, 6);
                }
            }
            __builtin_amdgcn_s_barrier();
            __builtin_amdgcn_s_setprio(1);
            #pragma unroll
            for (int j = 0; j < 4; j++)
                #pragma unroll
                for (int nt = 0; nt < 3; nt++)
                    acc[mh * 4 + j][nt] = mfma16(af[j], bfr[nt], acc[mh * 4 + j][nt]);
            __builtin_amdgcn_s_setprio(0);
            if (q == 3 && t < 15)
                __builtin_amdgcn_s_waitcnt(WAITCNT_VM(0));  // tile t+1 landed
            __builtin_amdgcn_s_barrier();
        }
    }

    // ---- epilogue: per-nt tensor dispatch (Q/K scatter; V to permuted vtg) ----
    int row0 = (int)am0 + wm_id * 128;           // multiple of 128
    int bb_ = row0 >> 11;
    int blkb = (row0 & 2047) >> 6;
    #pragma unroll
    for (int nt = 0; nt < 3; nt++) {
        int n = (int)wn0 + wn_id * 48 + nt * 16 + lrow;
        int tensor = n >> 10;                    // 0=Q 1=K 2=V (uniform per nt-tile)
        int np = n & 1023;                       // n' = h*64+d
        int h = np >> 6, d = np & 63;
        const float* bias = tensor == 0 ? bq : tensor == 1 ? bk : bv;
        float bbv = bias[d * 16 + h];
        float scale = tensor == 0 ? QSCALE : 1.0f;
        if (tensor < 2) {
            unsigned short* outt = out_bf + (size_t)tensor * (32u * T_SEQ * DH);
            #pragma unroll
            for (int mt = 0; mt < 8; mt++) {
                #pragma unroll
                for (int r = 0; r < 4; r++) {
                    int row = row0 + mt * 16 + lq * 4 + r;
                    float v = (acc[mt][nt][r] + bbv) * scale;
                    int b = row >> 11, i = row & 2047;
                    long idx = ((long)(b * 16 + h) * T_SEQ + i) * DH + d;
                    outt[idx] = f32_bf16(v);
                }
            }
        } else {
            // vtg j'-slot permutation (within each 64-token block): position
            // g*32 + lq*8 + nt'*4 + r holds token (g*2+nt')*16 + lq*4 + r.
            #pragma unroll
            for (int mt = 0; mt < 8; mt++) {
                int blk = blkb + (mt >> 2);
                int m4 = mt & 3;
                long base = (((long)(bb_ * 16 + h) * 64 + d) * 32 + blk) * 64;
                uint2 o;
                o.x = pack2_bf16(acc[mt][nt][0] + bbv, acc[mt][nt][1] + bbv);
                o.y = pack2_bf16(acc[mt][nt][2] + bbv, acc[mt][nt][3] + bbv);
                *(uint2*)(vtg + base + (m4 >> 1) * 32 + lq * 8 + (m4 & 1) * 4) = o;
            }
        }
    }
}

// ---------------- O-proj GEMM: ring-3 LDS, 2-tile prefetch depth (r14) ----------------
template <int BN, int MODE>
__global__ __launch_bounds__(256) void k_gemm(const unsigned short* __restrict__ A,
                                              const unsigned short* __restrict__ W,
                                              const float* __restrict__ b0,
                                              const float* __restrict__ resid,
                                              float* __restrict__ out_f32) {
    constexpr int NT = BN / 32;
    constexpr int NCB = BN / 32;
    __shared__ unsigned short lds_a[3 * 128 * 64];
    __shared__ unsigned short lds_b[3 * BN * 64];
    const int tid = threadIdx.x;
    const int w = tid >> 6, l = tid & 63;
    const int lrow = l & 15, lq = l >> 4;
    const int wm = (w >> 1) * 64, wn = (w & 1) * (BN / 2);
    const int L = blockIdx.x;
    const int bx = (L & 7) * 4 + ((L >> 3) & 3);
    const int by = L >> 5;
    const long am0 = (long)bx * 128;
    const long wn0 = (long)by * BN;

    floatx4 acc[4][NT] = {};
    const int grow = l >> 3;
    const int gcol = ((l & 7) ^ grow) * 8;   // column-group XOR swizzle (global side)
    const int sw8 = (lrow & 7);

    auto stage = [&](int ki, int sel) {
        unsigned short* la = lds_a + sel * 8192;
        unsigned short* lb = lds_b + sel * (BN * 64);
        int k0 = ki * 64;
        #pragma unroll
        for (int c = 0; c < 4; c++) {
            int chunk = w * 4 + c;
            gl2lds16(A + (am0 + chunk * 8 + grow) * D_MODEL + k0 + gcol, la + chunk * 512);
        }
        #pragma unroll
        for (int c = 0; c < NCB; c++) {
            int chunk = w * NCB + c;
            gl2lds16(W + (wn0 + chunk * 8 + grow) * D_MODEL + k0 + gcol, lb + chunk * 512);
        }
    };

    auto compute = [&](const unsigned short* la, const unsigned short* lb) {
        bf16x8 af[4][2], bfr[NT][2];
        #pragma unroll
        for (int mt = 0; mt < 4; mt++)
            #pragma unroll
            for (int ks = 0; ks < 2; ks++)
                af[mt][ks] = *(const bf16x8*)(la + (wm + mt * 16 + lrow) * 64 +
                                              (((ks * 4 + lq) ^ sw8) * 8));
        #pragma unroll
        for (int nt = 0; nt < NT; nt++)
            #pragma unroll
            for (int ks = 0; ks < 2; ks++)
                bfr[nt][ks] = *(const bf16x8*)(lb + (wn + nt * 16 + lrow) * 64 +
                                               (((ks * 4 + lq) ^ sw8) * 8));
        #pragma unroll
        for (int mt = 0; mt < 4; mt++)
            #pragma unroll
            for (int nt = 0; nt < NT; nt++)
                #pragma unroll
                for (int ks = 0; ks < 2; ks++)
                    acc[mt][nt] = mfma16(af[mt][ks], bfr[nt][ks], acc[mt][nt]);
    };

    stage(0, 0);
    stage(1, 1);
    for (int i = 0; i < 16; i++) {
        const int sel = i % 3;
        if (i < 14) {
            stage(i + 2, (i + 2) % 3);
            __builtin_amdgcn_s_waitcnt(WAITCNT_VM(12));  // drain S(i), keep S(i+1),S(i+2)
        } else if (i == 14) {
            __builtin_amdgcn_s_waitcnt(WAITCNT_VM(6));   // drain S(14), keep S(15)
        } else {
            __builtin_amdgcn_s_waitcnt(WAITCNT_VM(0));   // drain S(15)
        }
        __builtin_amdgcn_s_barrier();
        compute(lds_a + sel * 8192, lds_b + sel * (BN * 64));
        __builtin_amdgcn_s_barrier();   // certifies compute(i) done -> slot i%3 reusable by S(i+3)
    }

    #pragma unroll
    for (int mt = 0; mt < 4; mt++) {
        #pragma unroll
        for (int nt = 0; nt < NT; nt++) {
            int n = (int)wn0 + wn + nt * 16 + lrow;
            float bb = b0[n];
            #pragma unroll
            for (int r = 0; r < 4; r++) {
                int row = (int)am0 + wm + mt * 16 + lq * 4 + r;
                long idx = (long)row * D_MODEL + n;
                out_f32[idx] = acc[mt][nt][r] + bb + resid[idx];
            }
        }
    }
}

// ---------------- attention: ring-4 LDS + single-barrier counted-vmcnt pipeline --------
// r13 structure (measured best: 44.0us). FROZEN.
__global__ __launch_bounds__(256) void k_attn(const unsigned short* __restrict__ q_ws,
                                              const unsigned short* __restrict__ k_ws,
                                              const unsigned short* __restrict__ vtg,
                                              unsigned short* __restrict__ att) {
    __shared__ unsigned short kbuf[4 * 4096];
    __shared__ unsigned short vbuf[4 * 4096];
    const int tid = threadIdx.x;
    const int w = tid >> 6, l = tid & 63;
    const int lrow = l & 15, lq = l >> 4;
    const int sw = lrow & 7;
    const int L = blockIdx.x;
    const int bh = (L & 7) * 4 + ((L >> 3) & 3);   // 4 bh per XCD -> K/V L2-resident
    const int i0 = (L >> 5) * 128;
    const unsigned short* kh = k_ws + (long)bh * T_SEQ * DH;
    const unsigned short* vh = vtg + (long)bh * 64 * T_SEQ;  // [d][blk][j'-permuted]

    const int rl = l >> 3;                     // staging: row within 8-row chunk
    const int gl = ((l & 7) ^ rl) * 8;         // staging: swizzled granule (shorts)

    bf16x8 qf[2][2];
    #pragma unroll
    for (int qt = 0; qt < 2; qt++) {
        const unsigned short* qp =
            q_ws + ((long)bh * T_SEQ + i0 + w * 32 + qt * 16 + lrow) * DH + lq * 8;
        qf[qt][0] = *(const bf16x8*)qp;
        qf[qt][1] = *(const bf16x8*)(qp + 32);
    }
    floatx4 o_acc[2][4] = {};
    floatx4 l_acc[2] = {};
    const short8v ones8s = {0x3F80, 0x3F80, 0x3F80, 0x3F80, 0x3F80, 0x3F80, 0x3F80, 0x3F80};
    const bf16x8 ones8 = as_bf(ones8s);

    // one K/V tile stage: 4 DMA instrs per thread (2 K + 2 V)
    auto stage = [&](int jt, int sel) {
        unsigned short* kd = kbuf + sel * 4096 + (w * 2) * 512;
        unsigned short* vd = vbuf + sel * 4096 + (w * 2) * 512;
        #pragma unroll
        for (int c = 0; c < 2; c++) {
            int row = w * 16 + c * 8 + rl;     // 0..63
            gl2lds16(kh + ((long)(jt * 64 + row)) * 64 + gl, kd + c * 512);
        }
        #pragma unroll
        for (int c = 0; c < 2; c++) {
            int row = w * 16 + c * 8 + rl;
            gl2lds16(vh + ((long)row * 32 + jt) * 64 + gl, vd + c * 512);
        }
    };

    // p = exp2(s); pack 4 bf16 (truncation via perm)
    auto sp4 = [&](floatx4 s) -> short4v {
        float p0 = __builtin_amdgcn_exp2f(s[0]);
        float p1 = __builtin_amdgcn_exp2f(s[1]);
        float p2 = __builtin_amdgcn_exp2f(s[2]);
        float p3 = __builtin_amdgcn_exp2f(s[3]);
        uint2 pk;
        pk.x = __builtin_amdgcn_perm(__float_as_uint(p1), __float_as_uint(p0), 0x07060302);
        pk.y = __builtin_amdgcn_perm(__float_as_uint(p3), __float_as_uint(p2), 0x07060302);
        union { uint2 u; short4v s4; } cv; cv.u = pk;
        return cv.s4;
    };

    // O^T += V^T * P for one dt, both q-tiles, K=32 (two j-halves g=0/1)
    auto pv_dt = [&](const unsigned short* vb_, int dt,
                     short8v (&p0)[2], short8v (&p1)[2]) {
        const unsigned short* vp = vb_ + (dt * 16 + lrow) * 64;
        bf16x8 vg0 = *(const bf16x8*)(vp + ((lq ^ sw) * 8));         // granule lq   (j 0..31)
        bf16x8 vg1 = *(const bf16x8*)(vp + (((4 + lq) ^ sw) * 8));   // granule 4+lq (j 32..63)
        o_acc[0][dt] = mfma16(vg0, as_bf(p0[0]), o_acc[0][dt]);
        o_acc[0][dt] = mfma16(vg1, as_bf(p0[1]), o_acc[0][dt]);
        o_acc[1][dt] = mfma16(vg0, as_bf(p1[0]), o_acc[1][dt]);
        o_acc[1][dt] = mfma16(vg1, as_bf(p1[1]), o_acc[1][dt]);
    };

    stage(0, 0);
    stage(1, 1);

    for (int t = 0; t < 32; t++) {
        const int sl = t & 3;
        if (t < 30) stage(t + 2, (t + 2) & 3);
        if (t < 30)
            __builtin_amdgcn_s_waitcnt(WAITCNT_VM(8));   // drain S(t), keep S(t+1),S(t+2)
        else if (t == 30)
            __builtin_amdgcn_s_waitcnt(WAITCNT_VM(4));   // drain S(30), keep S(31)
        else
            __builtin_amdgcn_s_waitcnt(WAITCNT_VM(0));   // drain S(31)
        __builtin_amdgcn_s_barrier();                    // all waves' S(t) landed

        const unsigned short* kb_ = kbuf + sl * 4096;
        const unsigned short* vb_ = vbuf + sl * 4096;

        // QK^T with sp4 of the previous nt-group interleaved (TRANS under MFMA)
        floatx4 s0[4], s1[4];
        short4v u0[4], u1[4];
        #pragma unroll
        for (int nt = 0; nt < 4; nt++) {
            const unsigned short* kp = kb_ + (nt * 16 + lrow) * 64;
            bf16x8 ka = *(const bf16x8*)(kp + ((lq ^ sw) * 8));
            bf16x8 kb2 = *(const bf16x8*)(kp + (((lq + 4) ^ sw) * 8));
            floatx4 c0 = {-EXP2_SHIFT, -EXP2_SHIFT, -EXP2_SHIFT, -EXP2_SHIFT};
            floatx4 c1 = c0;
            c0 = mfma16(ka, qf[0][0], c0);
            c0 = mfma16(kb2, qf[0][1], c0);
            c1 = mfma16(ka, qf[1][0], c1);
            c1 = mfma16(kb2, qf[1][1], c1);
            s0[nt] = c0;
            s1[nt] = c1;
            if (nt > 0) {
                u0[nt - 1] = sp4(s0[nt - 1]);
                u1[nt - 1] = sp4(s1[nt - 1]);
            }
        }
        u0[3] = sp4(s0[3]);
        u1[3] = sp4(s1[3]);
        short8v pf0[2], pf1[2];
        pf0[0] = __builtin_shufflevector(u0[0], u0[1], 0, 1, 2, 3, 4, 5, 6, 7);
        pf0[1] = __builtin_shufflevector(u0[2], u0[3], 0, 1, 2, 3, 4, 5, 6, 7);
        pf1[0] = __builtin_shufflevector(u1[0], u1[1], 0, 1, 2, 3, 4, 5, 6, 7);
        pf1[1] = __builtin_shufflevector(u1[2], u1[3], 0, 1, 2, 3, 4, 5, 6, 7);
        // pure-MFMA burst: l_acc (4) + PV (16) — boost arbitration priority
        __builtin_amdgcn_s_setprio(1);
        l_acc[0] = mfma16(ones8, as_bf(pf0[0]), l_acc[0]);
        l_acc[0] = mfma16(ones8, as_bf(pf0[1]), l_acc[0]);
        l_acc[1] = mfma16(ones8, as_bf(pf1[0]), l_acc[1]);
        l_acc[1] = mfma16(ones8, as_bf(pf1[1]), l_acc[1]);
        #pragma unroll
        for (int dt = 0; dt < 4; dt++) pv_dt(vb_, dt, pf0, pf1);
        __builtin_amdgcn_s_setprio(0);
        // no trailing barrier: ring-4 slot discipline covers restage safety
    }

    int h = bh & 15, b = bh >> 4;
    #pragma unroll
    for (int qt = 0; qt < 2; qt++) {
        float rl2 = 1.0f / l_acc[qt][0];
        int i = i0 + w * 32 + qt * 16 + lrow;
        unsigned short* orow = att + ((long)(b * T_SEQ + i)) * D_MODEL + h * 64;
        #pragma unroll
        for (int dt = 0; dt < 4; dt++) {
            uint2 o;
            o.x = pack2_bf16(o_acc[qt][dt][0] * rl2, o_acc[qt][dt][1] * rl2);
            o.y = pack2_bf16(o_acc[qt][dt][2] * rl2, o_acc[qt][dt][3] * rl2);
            *(uint2*)(orow + dt * 16 + lq * 4) = o;
        }
    }
}

// ---------------- LayerNorm in-place on d_out ----------------
__global__ __launch_bounds__(256) void k_ln(float* __restrict__ io,
                                            const float* __restrict__ gamma,
                                            const float* __restrict__ beta) {
    int row = blockIdx.x, t = threadIdx.x;
    float* p = io + (long)row * D_MODEL + t * 4;
    float4 v = *(float4*)p;
    float s = v.x + v.y + v.z + v.w;
    float ss = v.x * v.x + v.y * v.y + v.z * v.z + v.w * v.w;
    #pragma unroll
    for (int m = 1; m < 64; m <<= 1) {
        s += __shfl_xor(s, m);
        ss += __shfl_xor(ss, m);
    }
    __shared__ float red[8];
    if ((t & 63) == 0) { red[t >> 6] = s; red[4 + (t >> 6)] = ss; }
    __syncthreads();
    s = red[0] + red[1] + red[2] + red[3];
    ss = red[4] + red[5] + red[6] + red[7];
    float mu = s * (1.0f / 1024.0f);
    float var = ss * (1.0f / 1024.0f) - mu * mu;
    float rstd = rsqrtf(var + 1e-5f);
    float4 g = *(const float4*)(gamma + t * 4);
    float4 be = *(const float4*)(beta + t * 4);
    float4 o;
    o.x = (v.x - mu) * rstd * g.x + be.x;
    o.y = (v.y - mu) * rstd * g.y + be.y;
    o.z = (v.z - mu) * rstd * g.z + be.z;
    o.w = (v.w - mu) * rstd * g.w + be.w;
    *(float4*)p = o;
}

extern "C" void kernel_launch(void* const* d_in, const int* in_sizes, int n_in,
                              void* d_out, int out_size, void* d_ws, size_t ws_size,
                              hipStream_t stream) {
    const float* x = (const float*)d_in[0];
    const float* Wq = (const float*)d_in[1];
    const float* bq = (const float*)d_in[2];
    const float* Wk = (const float*)d_in[3];
    const float* bk = (const float*)d_in[4];
    const float* Wv = (const float*)d_in[5];
    const float* bv = (const float*)d_in[6];
    const float* Wo = (const float*)d_in[7];
    const float* bo = (const float*)d_in[8];
    const float* gamma = (const float*)d_in[9];
    const float* beta = (const float*)d_in[10];
    float* out = (float*)d_out;

    char* ws = (char*)d_ws;
    unsigned short* x_bf = (unsigned short*)(ws);                       // 0-8 MB (reused as att)
    unsigned short* wqkv_bf = (unsigned short*)(ws + ((size_t)8 << 20));// 8-14 MB
    unsigned short* wo_bf = (unsigned short*)(ws + ((size_t)14 << 20)); // 14-16 MB
    unsigned short* qkv_ws = (unsigned short*)(ws + ((size_t)16 << 20));// 16-40 MB (q|k|vt)
    unsigned short* att = x_bf;  // alias: x_bf dead after QKV GEMM

    unsigned short* q_ws = qkv_ws;
    unsigned short* k_ws = qkv_ws + (size_t)32 * T_SEQ * DH;
    unsigned short* vtg = qkv_ws + (size_t)64 * T_SEQ * DH;

    k_conv_all<<<8192, 256, 0, stream>>>(x, Wq, Wk, Wv, Wo, x_bf, wqkv_bf, wo_bf);

    // fused QKV GEMM: 256x192 tiles, N = 3072, grid 256 (16x16, XCD-interleaved)
    k_qkv256<<<256, 512, 0, stream>>>(x_bf, wqkv_bf, bq, bk, bv, qkv_ws, vtg);

    k_attn<<<512, 256, 0, stream>>>(q_ws, k_ws, vtg, att);

    // O-projection + bias + residual: N = 1024, 1D grid with XCD swizzle
    k_gemm<64, 1><<<512, 256, 0, stream>>>(
        att, wo_bf, bo, x, out);

    k_ln<<<NROWS, 256, 0, stream>>>(out, gamma, beta);
}